// Round 2
// baseline (4489.116 us; speedup 1.0000x reference)
//
#include <hip/hip_runtime.h>
#include <cstdint>

#define B_ 2
#define S_ 4096
#define H_ 2048
#define NH_ 16
#define HD_ 128
#define BLOCK_ 256
#define NC_ (S_/BLOCK_)   // 16
#define M_ (B_*S_)        // 8192
#define EPS_ 1e-5f

typedef unsigned short ushort_t;
struct ushort4_t { ushort_t x, y, z, w; };

static __device__ inline float bf2f(ushort_t u) {
    union { unsigned int i; float f; } x;
    x.i = ((unsigned int)u) << 16;
    return x.f;
}
static __device__ inline ushort_t f2bf(float f) {
    union { float f; unsigned int i; } x;
    x.f = f;
    unsigned int r = x.i + 0x7fffu + ((x.i >> 16) & 1u);
    return (ushort_t)(r >> 16);
}

// ---------------------------------------------------------------------------
// GEMM with f32 A/B (hidden @ weights), 128x128 tile, BK=16, 256 thr, 8x8.
// MODE 1: sigmoid -> bf16 C
// MODE 2: silu -> scatter bf16 q/k/v head layout (B,NH,S,HD); v *= mask
// ---------------------------------------------------------------------------
template<int MODE>
__global__ __launch_bounds__(256)
void gemm_h(const float* __restrict__ A, const float* __restrict__ Bm,
            ushort_t* __restrict__ C, int M, int N, int K,
            ushort_t* __restrict__ qout, ushort_t* __restrict__ kout,
            ushort_t* __restrict__ vout, const float* __restrict__ mask)
{
    __shared__ __align__(16) float As[16][132];
    __shared__ __align__(16) float Bs[16][132];
    const int tid = threadIdx.x;
    const int tx = tid & 15, ty = tid >> 4;
    const int rowBase = blockIdx.y * 128, colBase = blockIdx.x * 128;
    const float* Ap = A + (size_t)rowBase * K;
    const float* Bp = Bm + colBase;

    float acc[8][8];
    #pragma unroll
    for (int i = 0; i < 8; ++i)
        #pragma unroll
        for (int j = 0; j < 8; ++j) acc[i][j] = 0.f;

    const int nk = K >> 4;
    for (int kt = 0; kt < nk; ++kt) {
        __syncthreads();
        #pragma unroll
        for (int i = 0; i < 2; ++i) {
            int lin4 = tid + i * 256;            // 0..511
            int r  = lin4 >> 2, k4 = lin4 & 3;
            float4 a4 = *reinterpret_cast<const float4*>(Ap + (size_t)r * K + kt * 16 + k4 * 4);
            As[k4 * 4 + 0][r] = a4.x;
            As[k4 * 4 + 1][r] = a4.y;
            As[k4 * 4 + 2][r] = a4.z;
            As[k4 * 4 + 3][r] = a4.w;
            int bk = lin4 >> 5, c4 = lin4 & 31;
            *reinterpret_cast<float4*>(&Bs[bk][c4 * 4]) =
                *reinterpret_cast<const float4*>(Bp + (size_t)(kt * 16 + bk) * N + c4 * 4);
        }
        __syncthreads();
        #pragma unroll
        for (int kk = 0; kk < 16; ++kk) {
            float4 a0 = *reinterpret_cast<const float4*>(&As[kk][ty * 4]);
            float4 a1 = *reinterpret_cast<const float4*>(&As[kk][64 + ty * 4]);
            float4 b0 = *reinterpret_cast<const float4*>(&Bs[kk][tx * 4]);
            float4 b1 = *reinterpret_cast<const float4*>(&Bs[kk][64 + tx * 4]);
            float a[8] = {a0.x, a0.y, a0.z, a0.w, a1.x, a1.y, a1.z, a1.w};
            float b[8] = {b0.x, b0.y, b0.z, b0.w, b1.x, b1.y, b1.z, b1.w};
            #pragma unroll
            for (int i = 0; i < 8; ++i)
                #pragma unroll
                for (int j = 0; j < 8; ++j)
                    acc[i][j] = fmaf(a[i], b[j], acc[i][j]);
        }
    }

    #pragma unroll
    for (int i = 0; i < 8; ++i) {
        int row = rowBase + ((i < 4) ? (ty * 4 + i) : (64 + ty * 4 + i - 4));
        #pragma unroll
        for (int j = 0; j < 8; ++j) {
            int col = colBase + ((j < 4) ? (tx * 4 + j) : (64 + tx * 4 + j - 4));
            float x = acc[i][j];
            if (MODE == 1) {
                C[(size_t)row * N + col] = f2bf(1.f / (1.f + expf(-x)));
            } else {
                float sv = x / (1.f + expf(-x));       // silu
                int which = col >> 11;                  // 0:q 1:k 2:v
                int h = (col >> 7) & 15;
                int d = col & 127;
                int b = row >> 12;
                int srow = row & 4095;
                size_t dst = ((size_t)(b * NH_ + h) * S_ + srow) * HD_ + d;
                if (which == 0)      qout[dst] = f2bf(sv);
                else if (which == 1) kout[dst] = f2bf(sv);
                else                 vout[dst] = f2bf(sv * mask[b * S_ + srow]);
            }
        }
    }
}

// ---------------------------------------------------------------------------
// Final GEMM: C[MxN] = A(bf16)[MxK] @ B(f32)[KxN], f32 out.
// ---------------------------------------------------------------------------
__global__ __launch_bounds__(256)
void gemm_o(const ushort_t* __restrict__ A, const float* __restrict__ Bm,
            float* __restrict__ C, int M, int N, int K)
{
    __shared__ __align__(16) float As[16][132];
    __shared__ __align__(16) float Bs[16][132];
    const int tid = threadIdx.x;
    const int tx = tid & 15, ty = tid >> 4;
    const int rowBase = blockIdx.y * 128, colBase = blockIdx.x * 128;
    const ushort_t* Ap = A + (size_t)rowBase * K;
    const float* Bp = Bm + colBase;

    float acc[8][8];
    #pragma unroll
    for (int i = 0; i < 8; ++i)
        #pragma unroll
        for (int j = 0; j < 8; ++j) acc[i][j] = 0.f;

    const int nk = K >> 4;
    for (int kt = 0; kt < nk; ++kt) {
        __syncthreads();
        #pragma unroll
        for (int i = 0; i < 2; ++i) {
            int lin4 = tid + i * 256;            // 0..511
            int r  = lin4 >> 2, k4 = lin4 & 3;
            ushort4_t a4 = *reinterpret_cast<const ushort4_t*>(Ap + (size_t)r * K + kt * 16 + k4 * 4);
            As[k4 * 4 + 0][r] = bf2f(a4.x);
            As[k4 * 4 + 1][r] = bf2f(a4.y);
            As[k4 * 4 + 2][r] = bf2f(a4.z);
            As[k4 * 4 + 3][r] = bf2f(a4.w);
            int bk = lin4 >> 5, c4 = lin4 & 31;
            *reinterpret_cast<float4*>(&Bs[bk][c4 * 4]) =
                *reinterpret_cast<const float4*>(Bp + (size_t)(kt * 16 + bk) * N + c4 * 4);
        }
        __syncthreads();
        #pragma unroll
        for (int kk = 0; kk < 16; ++kk) {
            float4 a0 = *reinterpret_cast<const float4*>(&As[kk][ty * 4]);
            float4 a1 = *reinterpret_cast<const float4*>(&As[kk][64 + ty * 4]);
            float4 b0 = *reinterpret_cast<const float4*>(&Bs[kk][tx * 4]);
            float4 b1 = *reinterpret_cast<const float4*>(&Bs[kk][64 + tx * 4]);
            float a[8] = {a0.x, a0.y, a0.z, a0.w, a1.x, a1.y, a1.z, a1.w};
            float b[8] = {b0.x, b0.y, b0.z, b0.w, b1.x, b1.y, b1.z, b1.w};
            #pragma unroll
            for (int i = 0; i < 8; ++i)
                #pragma unroll
                for (int j = 0; j < 8; ++j)
                    acc[i][j] = fmaf(a[i], b[j], acc[i][j]);
        }
    }

    #pragma unroll
    for (int i = 0; i < 8; ++i) {
        int row = rowBase + ((i < 4) ? (ty * 4 + i) : (64 + ty * 4 + i - 4));
        #pragma unroll
        for (int j = 0; j < 8; ++j) {
            int col = colBase + ((j < 4) ? (tx * 4 + j) : (64 + tx * 4 + j - 4));
            C[(size_t)row * N + col] = acc[i][j];
        }
    }
}

// ---------------------------------------------------------------------------
// Per-chunk KV contribution: KV_c[d][e] = sum_n k[n][d]*exp(-s*(255-n))*v[n][e]
// ---------------------------------------------------------------------------
__global__ __launch_bounds__(256)
void kv_chunk_kernel(const ushort_t* __restrict__ k, const ushort_t* __restrict__ v,
                     const float* __restrict__ slope, float* __restrict__ kvc)
{
    const int c = blockIdx.x, bh = blockIdx.y;
    const float s = slope[bh & 15];
    const int tid = threadIdx.x, tx = tid & 15, ty = tid >> 4;
    __shared__ __align__(16) float kt[32][132];
    __shared__ __align__(16) float vt[32][132];
    const ushort_t* kb = k + ((size_t)bh * S_ + (size_t)c * BLOCK_) * HD_;
    const ushort_t* vb = v + ((size_t)bh * S_ + (size_t)c * BLOCK_) * HD_;

    float acc[8][8];
    #pragma unroll
    for (int i = 0; i < 8; ++i)
        #pragma unroll
        for (int j = 0; j < 8; ++j) acc[i][j] = 0.f;

    for (int nt = 0; nt < 8; ++nt) {
        __syncthreads();
        #pragma unroll
        for (int i = 0; i < 4; ++i) {
            int lin4 = tid + i * 256;          // 0..1023 over 32 rows x 32 groups
            int r = lin4 >> 5, d4 = lin4 & 31;
            int n = nt * 32 + r;
            float dec = expf(-s * (float)(BLOCK_ - 1 - n));
            ushort4_t k4 = *reinterpret_cast<const ushort4_t*>(kb + (size_t)n * HD_ + d4 * 4);
            ushort4_t v4 = *reinterpret_cast<const ushort4_t*>(vb + (size_t)n * HD_ + d4 * 4);
            float4 kf = { bf2f(k4.x) * dec, bf2f(k4.y) * dec, bf2f(k4.z) * dec, bf2f(k4.w) * dec };
            float4 vf = { bf2f(v4.x), bf2f(v4.y), bf2f(v4.z), bf2f(v4.w) };
            *reinterpret_cast<float4*>(&kt[r][d4 * 4]) = kf;
            *reinterpret_cast<float4*>(&vt[r][d4 * 4]) = vf;
        }
        __syncthreads();
        #pragma unroll
        for (int nn = 0; nn < 32; ++nn) {
            float a[8], b[8];
            #pragma unroll
            for (int i = 0; i < 4; ++i) { a[i] = kt[nn][ty * 4 + i]; a[i + 4] = kt[nn][64 + ty * 4 + i]; }
            #pragma unroll
            for (int j = 0; j < 4; ++j) { b[j] = vt[nn][tx * 4 + j]; b[j + 4] = vt[nn][64 + tx * 4 + j]; }
            #pragma unroll
            for (int i = 0; i < 8; ++i)
                #pragma unroll
                for (int j = 0; j < 8; ++j)
                    acc[i][j] = fmaf(a[i], b[j], acc[i][j]);
        }
    }
    float* out = kvc + (((size_t)bh * NC_ + c) << 14);
    #pragma unroll
    for (int i = 0; i < 8; ++i) {
        int d = (i < 4) ? (ty * 4 + i) : (64 + ty * 4 + i - 4);
        #pragma unroll
        for (int j = 0; j < 8; ++j) {
            int e = (j < 4) ? (tx * 4 + j) : (64 + tx * 4 + j - 4);
            out[(size_t)d * 128 + e] = acc[i][j];
        }
    }
}

// ---------------------------------------------------------------------------
// Prefix scan over chunks: S_0 = 0; S_{c+1} = bd*S_c + KV_c (in place).
// ---------------------------------------------------------------------------
__global__ __launch_bounds__(256)
void kv_scan_kernel(const float* __restrict__ slope, float* __restrict__ kvc)
{
    const int es = blockIdx.x, bh = blockIdx.y;
    const float s = slope[bh & 15];
    const float bd = expf(-s * (float)BLOCK_);
    const int tid = threadIdx.x;
    float st[16];
    #pragma unroll
    for (int i = 0; i < 16; ++i) st[i] = 0.f;
    float* base = kvc + ((size_t)(bh * NC_) << 14);
    for (int c = 0; c < NC_; ++c) {
        float* p = base + ((size_t)c << 14);
        #pragma unroll
        for (int i = 0; i < 16; ++i) {
            int lin = tid + i * 256;                    // 0..4095
            int off = (lin >> 5) * 128 + es * 32 + (lin & 31);
            float x = p[off];
            p[off] = st[i];
            st[i] = bd * st[i] + x;
        }
    }
}

// ---------------------------------------------------------------------------
// Per-chunk output -> o (f32, B x S x 2048 layout, written into d_out scratch)
// ---------------------------------------------------------------------------
__global__ __launch_bounds__(256)
void attn_out_kernel(const ushort_t* __restrict__ q, const ushort_t* __restrict__ k,
                     const ushort_t* __restrict__ v, const float* __restrict__ kvs,
                     const float* __restrict__ slope, float* __restrict__ o)
{
    const int c = blockIdx.x, bh = blockIdx.y;
    const int h = bh & 15, b = bh >> 4;
    const float s = slope[h];
    const int tid = threadIdx.x, tx = tid & 15, ty = tid >> 4;
    __shared__ __align__(16) float Qp[64][132];
    __shared__ __align__(16) float Tt[64][132];
    __shared__ __align__(16) float Am[64][260];
    const ushort_t* qb = q + ((size_t)bh * S_ + (size_t)c * BLOCK_) * HD_;
    const ushort_t* kb = k + ((size_t)bh * S_ + (size_t)c * BLOCK_) * HD_;
    const ushort_t* vb = v + ((size_t)bh * S_ + (size_t)c * BLOCK_) * HD_;
    const float* Sc = kvs + (((size_t)bh * NC_ + c) << 14);

    for (int p = 0; p < 4; ++p) {
        __syncthreads();
        #pragma unroll
        for (int i = 0; i < 8; ++i) {
            int lin4 = tid + i * 256;          // 0..2047 over 64 rows x 32 groups
            int r = lin4 >> 5, d4 = lin4 & 31;
            ushort4_t x4 = *reinterpret_cast<const ushort4_t*>(qb + (size_t)(p * 64 + r) * HD_ + d4 * 4);
            float4 xf = { bf2f(x4.x), bf2f(x4.y), bf2f(x4.z), bf2f(x4.w) };
            *reinterpret_cast<float4*>(&Qp[r][d4 * 4]) = xf;
        }
        // ----- phase A: Am = (Qp @ K^T) * diag_decay, 64 x 256 -----
        for (int nt = 0; nt < 4; ++nt) {
            __syncthreads();
            #pragma unroll
            for (int i = 0; i < 8; ++i) {
                int lin4 = tid + i * 256;
                int r = lin4 >> 5, d4 = lin4 & 31;
                ushort4_t x4 = *reinterpret_cast<const ushort4_t*>(kb + (size_t)(nt * 64 + r) * HD_ + d4 * 4);
                float4 xf = { bf2f(x4.x), bf2f(x4.y), bf2f(x4.z), bf2f(x4.w) };
                *reinterpret_cast<float4*>(&Tt[r][d4 * 4]) = xf;
            }
            __syncthreads();
            float pacc[4][4];
            #pragma unroll
            for (int i = 0; i < 4; ++i)
                #pragma unroll
                for (int j = 0; j < 4; ++j) pacc[i][j] = 0.f;
            #pragma unroll 4
            for (int d = 0; d < 128; ++d) {
                float a[4], bb[4];
                #pragma unroll
                for (int i = 0; i < 4; ++i) a[i]  = Qp[ty * 4 + i][d];
                #pragma unroll
                for (int j = 0; j < 4; ++j) bb[j] = Tt[tx * 4 + j][d];
                #pragma unroll
                for (int i = 0; i < 4; ++i)
                    #pragma unroll
                    for (int j = 0; j < 4; ++j)
                        pacc[i][j] = fmaf(a[i], bb[j], pacc[i][j]);
            }
            #pragma unroll
            for (int i = 0; i < 4; ++i) {
                int m = p * 64 + ty * 4 + i;
                #pragma unroll
                for (int j = 0; j < 4; ++j) {
                    int n = nt * 64 + tx * 4 + j;
                    float dec = (m >= n) ? expf(-s * (float)(m - n)) : 0.f;
                    Am[ty * 4 + i][nt * 64 + tx * 4 + j] = pacc[i][j] * dec;
                }
            }
        }
        // ----- phase B: oa = Am @ V ; ob = Qp @ S_c -----
        float oa[4][8], ob[4][8];
        #pragma unroll
        for (int i = 0; i < 4; ++i)
            #pragma unroll
            for (int j = 0; j < 8; ++j) { oa[i][j] = 0.f; ob[i][j] = 0.f; }

        for (int nt = 0; nt < 4; ++nt) {
            __syncthreads();
            #pragma unroll
            for (int i = 0; i < 8; ++i) {
                int lin4 = tid + i * 256;
                int r = lin4 >> 5, d4 = lin4 & 31;
                ushort4_t x4 = *reinterpret_cast<const ushort4_t*>(vb + (size_t)(nt * 64 + r) * HD_ + d4 * 4);
                float4 xf = { bf2f(x4.x), bf2f(x4.y), bf2f(x4.z), bf2f(x4.w) };
                *reinterpret_cast<float4*>(&Tt[r][d4 * 4]) = xf;
            }
            __syncthreads();
            #pragma unroll 4
            for (int n = 0; n < 64; ++n) {
                float a[4], vv[8];
                #pragma unroll
                for (int i = 0; i < 4; ++i) a[i] = Am[ty * 4 + i][nt * 64 + n];
                #pragma unroll
                for (int j = 0; j < 8; ++j)
                    vv[j] = Tt[n][(j < 4) ? (tx * 4 + j) : (64 + tx * 4 + j - 4)];
                #pragma unroll
                for (int i = 0; i < 4; ++i)
                    #pragma unroll
                    for (int j = 0; j < 8; ++j)
                        oa[i][j] = fmaf(a[i], vv[j], oa[i][j]);
            }
        }
        for (int dt = 0; dt < 2; ++dt) {
            __syncthreads();
            #pragma unroll
            for (int i = 0; i < 8; ++i) {
                int lin4 = tid + i * 256;
                int r = lin4 >> 5, d4 = lin4 & 31;
                *reinterpret_cast<float4*>(&Tt[r][d4 * 4]) =
                    *reinterpret_cast<const float4*>(Sc + (size_t)(dt * 64 + r) * 128 + d4 * 4);
            }
            __syncthreads();
            #pragma unroll 4
            for (int dd = 0; dd < 64; ++dd) {
                float a[4], sv[8];
                #pragma unroll
                for (int i = 0; i < 4; ++i) a[i] = Qp[ty * 4 + i][dt * 64 + dd];
                #pragma unroll
                for (int j = 0; j < 8; ++j)
                    sv[j] = Tt[dd][(j < 4) ? (tx * 4 + j) : (64 + tx * 4 + j - 4)];
                #pragma unroll
                for (int i = 0; i < 4; ++i)
                    #pragma unroll
                    for (int j = 0; j < 8; ++j)
                        ob[i][j] = fmaf(a[i], sv[j], ob[i][j]);
            }
        }
        #pragma unroll
        for (int i = 0; i < 4; ++i) {
            int m = p * 64 + ty * 4 + i;
            float qdec = expf(-s * (float)(m + 1));
            float* orow = o + ((size_t)(b * S_ + c * BLOCK_ + m)) * H_ + h * HD_;
            #pragma unroll
            for (int j = 0; j < 8; ++j) {
                int col = (j < 4) ? (tx * 4 + j) : (64 + tx * 4 + j - 4);
                orow[col] = oa[i][j] + qdec * ob[i][j];
            }
        }
    }
}

// ---------------------------------------------------------------------------
// RMSNorm * norm_weight * gate: reads f32 o (d_out scratch), writes bf16 o_n.
// ---------------------------------------------------------------------------
__global__ __launch_bounds__(256)
void norm_gate_kernel(const float* __restrict__ o, const ushort_t* __restrict__ gate,
                      const float* __restrict__ nw, ushort_t* __restrict__ on)
{
    const int row = blockIdx.x;
    const int tid = threadIdx.x;
    const float* orow = o + (size_t)row * H_;
    const ushort_t* grow = gate + (size_t)row * H_;
    ushort_t* onrow = on + (size_t)row * H_;
    float vals[8];
    float ss = 0.f;
    #pragma unroll
    for (int i = 0; i < 8; ++i) {
        vals[i] = orow[tid + i * 256];
        ss += vals[i] * vals[i];
    }
    __shared__ float red[256];
    red[tid] = ss;
    __syncthreads();
    #pragma unroll
    for (int st = 128; st > 0; st >>= 1) {
        if (tid < st) red[tid] += red[tid + st];
        __syncthreads();
    }
    float scale = rsqrtf(red[0] * (1.f / (float)H_) + EPS_);
    #pragma unroll
    for (int i = 0; i < 8; ++i) {
        int cidx = tid + i * 256;
        onrow[cidx] = f2bf(vals[i] * scale * nw[cidx] * bf2f(grow[cidx]));
    }
}

// ---------------------------------------------------------------------------
extern "C" void kernel_launch(void* const* d_in, const int* in_sizes, int n_in,
                              void* d_out, int out_size, void* d_ws, size_t ws_size,
                              hipStream_t stream)
{
    const float* hidden = (const float*)d_in[0];
    const float* mask   = (const float*)d_in[1];
    const float* slope  = (const float*)d_in[2];
    const float* w_qkv  = (const float*)d_in[3];
    const float* w_gate = (const float*)d_in[4];
    const float* w_out  = (const float*)d_in[5];
    const float* nw     = (const float*)d_in[6];

    const size_t MH = (size_t)M_ * H_;                 // 16,777,216
    ushort_t* q_ws    = (ushort_t*)d_ws;               // bf16, MH each
    ushort_t* k_ws    = q_ws + MH;
    ushort_t* v_ws    = k_ws + MH;
    ushort_t* gate_ws = v_ws + MH;
    ushort_t* on_ws   = gate_ws + MH;
    float*    kv_ws   = (float*)(on_ws + MH);          // 8,388,608 f32
    float*    o_f32   = (float*)d_out;                 // pre-norm o scratch

    dim3 blk(256);
    // 1. qkv = silu(hidden @ w_qkv) -> bf16 q/k/v (head layout), v *= mask
    gemm_h<2><<<dim3(6144 / 128, M_ / 128), blk, 0, stream>>>(
        hidden, w_qkv, nullptr, M_, 6144, H_, q_ws, k_ws, v_ws, mask);
    // 2. gate = sigmoid(hidden @ w_gate) -> bf16
    gemm_h<1><<<dim3(H_ / 128, M_ / 128), blk, 0, stream>>>(
        hidden, w_gate, gate_ws, M_, H_, H_, nullptr, nullptr, nullptr, nullptr);
    // 3. per-chunk KV contributions (f32)
    kv_chunk_kernel<<<dim3(NC_, B_ * NH_), blk, 0, stream>>>(k_ws, v_ws, slope, kv_ws);
    // 4. prefix scan of KV states (in place)
    kv_scan_kernel<<<dim3(4, B_ * NH_), blk, 0, stream>>>(slope, kv_ws);
    // 5. attention outputs -> f32 o into d_out (scratch)
    attn_out_kernel<<<dim3(NC_, B_ * NH_), blk, 0, stream>>>(q_ws, k_ws, v_ws, kv_ws, slope, o_f32);
    // 6. RMSNorm * nw * gate -> bf16 o_n
    norm_gate_kernel<<<M_, blk, 0, stream>>>(o_f32, gate_ws, nw, on_ws);
    // 7. out = o_n @ w_out (overwrites d_out)
    gemm_o<<<dim3(H_ / 128, M_ / 128), blk, 0, stream>>>(on_ws, w_out, (float*)d_out, M_, H_, H_);
}

// Round 3
// 1165.257 us; speedup vs baseline: 3.8525x; 3.8525x over previous
//
#include <hip/hip_runtime.h>
#include <cstdint>

#define B_ 2
#define S_ 4096
#define H_ 2048
#define NH_ 16
#define HD_ 128
#define BLOCK_ 256
#define NC_ (S_/BLOCK_)   // 16
#define M_ (B_*S_)        // 8192
#define EPS_ 1e-5f

typedef unsigned short ushort_t;
struct ushort4_t { ushort_t x, y, z, w; };
typedef unsigned short u16x4 __attribute__((ext_vector_type(4)));
typedef short frag_ab __attribute__((ext_vector_type(8)));   // 8 bf16 (4 VGPRs)
typedef float frag_cd __attribute__((ext_vector_type(4)));   // 4 f32

static __device__ inline float bf2f(ushort_t u) {
    union { unsigned int i; float f; } x;
    x.i = ((unsigned int)u) << 16;
    return x.f;
}
static __device__ inline ushort_t f2bf(float f) {
    union { float f; unsigned int i; } x;
    x.f = f;
    unsigned int r = x.i + 0x7fffu + ((x.i >> 16) & 1u);
    return (ushort_t)(r >> 16);
}

// async global->LDS, 16B per lane; LDS dest is wave-uniform base + lane*16
static __device__ __forceinline__ void gload_lds16(const ushort_t* g, ushort_t* l) {
    __builtin_amdgcn_global_load_lds(
        (__attribute__((address_space(1))) void*)(uintptr_t)g,
        (__attribute__((address_space(3))) void*)l,
        16, 0, 0);
}

// ---------------------------------------------------------------------------
// Prep: f32 -> bf16 elementwise cast (hidden). n4 = elems/4.
// ---------------------------------------------------------------------------
__global__ __launch_bounds__(256)
void cast_bf16_kernel(const float* __restrict__ in, ushort_t* __restrict__ out)
{
    int i = blockIdx.x * 256 + threadIdx.x;
    float4 v = reinterpret_cast<const float4*>(in)[i];
    u16x4 o = { f2bf(v.x), f2bf(v.y), f2bf(v.z), f2bf(v.w) };
    *reinterpret_cast<u16x4*>(&out[(size_t)i * 4]) = o;
}

// ---------------------------------------------------------------------------
// Prep: W[K][N] f32 -> WT[N][K] bf16 (tiled transpose+cast).
// grid (N/32, K/32), 256 threads.
// ---------------------------------------------------------------------------
__global__ __launch_bounds__(256)
void transpose_cast_kernel(const float* __restrict__ W, ushort_t* __restrict__ WT,
                           int K, int N)
{
    __shared__ float t[32][33];
    const int kb = blockIdx.y * 32, nb = blockIdx.x * 32;
    const int tx = threadIdx.x & 31, ty = threadIdx.x >> 5;  // 32 x 8
    #pragma unroll
    for (int i = 0; i < 4; ++i)
        t[ty + i * 8][tx] = W[(size_t)(kb + ty + i * 8) * N + nb + tx];
    __syncthreads();
    #pragma unroll
    for (int i = 0; i < 4; ++i)
        WT[(size_t)(nb + ty + i * 8) * K + kb + tx] = f2bf(t[tx][ty + i * 8]);
}

// ---------------------------------------------------------------------------
// MFMA GEMM: A[M][K] bf16 row-major, BT[N][K] bf16 (pre-transposed B).
// 128x128 tile, BK=32, 4 waves (2x2), 16x16x32 bf16 MFMA, acc 4x4 frags/wave.
// MODE 0: f32 C.  MODE 1: sigmoid -> bf16 C.
// MODE 2: silu -> scatter bf16 q/k/v head layout (B,NH,S,HD); v *= mask.
// ---------------------------------------------------------------------------
template<int MODE>
__global__ __launch_bounds__(256)
void gemm_mfma(const ushort_t* __restrict__ A, const ushort_t* __restrict__ BT,
               int M, int N, int K,
               float* __restrict__ Cf, ushort_t* __restrict__ Cb,
               ushort_t* __restrict__ qo, ushort_t* __restrict__ ko,
               ushort_t* __restrict__ vo, const float* __restrict__ mask)
{
    __shared__ __align__(16) ushort_t As[128 * 32];   // [row][k] 8KB
    __shared__ __align__(16) ushort_t Bs[128 * 32];   // [col][k] 8KB
    const int tid  = threadIdx.x;
    const int lane = tid & 63, wid = tid >> 6;
    const int wr = wid >> 1, wc = wid & 1;            // wave quadrant
    const int l15 = lane & 15, l4 = lane >> 4;
    const int rowBase = blockIdx.y * 128, colBase = blockIdx.x * 128;

    // staging source coords: thread t covers row j*64 + t/4, k-offset (t&3)*8
    const int srow = tid >> 2;
    const int sk   = (tid & 3) * 8;

    frag_cd acc[4][4];
    #pragma unroll
    for (int m = 0; m < 4; ++m)
        #pragma unroll
        for (int n = 0; n < 4; ++n) acc[m][n] = 0.f;

    for (int kt = 0; kt < K; kt += 32) {
        __syncthreads();   // previous iter's LDS reads done
        #pragma unroll
        for (int j = 0; j < 2; ++j) {
            gload_lds16(A  + (size_t)(rowBase + j * 64 + srow) * K + kt + sk,
                        &As[j * 2048 + wid * 512]);
            gload_lds16(BT + (size_t)(colBase + j * 64 + srow) * K + kt + sk,
                        &Bs[j * 2048 + wid * 512]);
        }
        __syncthreads();   // compiler drains vmcnt(0) before barrier -> data visible

        frag_ab af[4], bf[4];
        #pragma unroll
        for (int m = 0; m < 4; ++m)
            af[m] = *reinterpret_cast<const frag_ab*>(&As[(wr * 64 + m * 16 + l15) * 32 + l4 * 8]);
        #pragma unroll
        for (int n = 0; n < 4; ++n)
            bf[n] = *reinterpret_cast<const frag_ab*>(&Bs[(wc * 64 + n * 16 + l15) * 32 + l4 * 8]);
        #pragma unroll
        for (int m = 0; m < 4; ++m)
            #pragma unroll
            for (int n = 0; n < 4; ++n)
                acc[m][n] = __builtin_amdgcn_mfma_f32_16x16x32_bf16(af[m], bf[n], acc[m][n], 0, 0, 0);
    }

    // epilogue: C/D layout col = lane&15, row = (lane>>4)*4 + reg  [m89/m91]
    const int orow0 = rowBase + wr * 64;
    const int ocol0 = colBase + wc * 64;
    if (MODE == 0) {
        #pragma unroll
        for (int m = 0; m < 4; ++m)
            #pragma unroll
            for (int n = 0; n < 4; ++n)
                #pragma unroll
                for (int r = 0; r < 4; ++r) {
                    int row = orow0 + m * 16 + l4 * 4 + r;
                    int col = ocol0 + n * 16 + l15;
                    Cf[(size_t)row * N + col] = acc[m][n][r];
                }
    } else if (MODE == 1) {
        #pragma unroll
        for (int m = 0; m < 4; ++m)
            #pragma unroll
            for (int n = 0; n < 4; ++n)
                #pragma unroll
                for (int r = 0; r < 4; ++r) {
                    int row = orow0 + m * 16 + l4 * 4 + r;
                    int col = ocol0 + n * 16 + l15;
                    float x = acc[m][n][r];
                    Cb[(size_t)row * N + col] = f2bf(1.f / (1.f + expf(-x)));
                }
    } else {
        const int which = colBase >> 11;          // block-uniform: 0:q 1:k 2:v
        const int h     = (colBase >> 7) & 15;
        ushort_t* outp = (which == 0) ? qo : ((which == 1) ? ko : vo);
        #pragma unroll
        for (int m = 0; m < 4; ++m)
            #pragma unroll
            for (int r = 0; r < 4; ++r) {
                int row = orow0 + m * 16 + l4 * 4 + r;
                int b = row >> 12, sr = row & 4095;
                float mk = (which == 2) ? mask[b * S_ + sr] : 1.f;
                #pragma unroll
                for (int n = 0; n < 4; ++n) {
                    int d = (ocol0 & 127) + n * 16 + l15;
                    float x = acc[m][n][r];
                    float sv = x / (1.f + expf(-x));          // silu
                    outp[((size_t)(b * NH_ + h) * S_ + sr) * HD_ + d] = f2bf(sv * mk);
                }
            }
    }
}

// ---------------------------------------------------------------------------
// Per-chunk KV contribution: KV_c[d][e] = sum_n k[n][d]*exp(-s*(255-n))*v[n][e]
// ---------------------------------------------------------------------------
__global__ __launch_bounds__(256)
void kv_chunk_kernel(const ushort_t* __restrict__ k, const ushort_t* __restrict__ v,
                     const float* __restrict__ slope, float* __restrict__ kvc)
{
    const int c = blockIdx.x, bh = blockIdx.y;
    const float s = slope[bh & 15];
    const int tid = threadIdx.x, tx = tid & 15, ty = tid >> 4;
    __shared__ __align__(16) float kt[32][132];
    __shared__ __align__(16) float vt[32][132];
    const ushort_t* kb = k + ((size_t)bh * S_ + (size_t)c * BLOCK_) * HD_;
    const ushort_t* vb = v + ((size_t)bh * S_ + (size_t)c * BLOCK_) * HD_;

    float acc[8][8];
    #pragma unroll
    for (int i = 0; i < 8; ++i)
        #pragma unroll
        for (int j = 0; j < 8; ++j) acc[i][j] = 0.f;

    for (int nt = 0; nt < 8; ++nt) {
        __syncthreads();
        #pragma unroll
        for (int i = 0; i < 4; ++i) {
            int lin4 = tid + i * 256;
            int r = lin4 >> 5, d4 = lin4 & 31;
            int n = nt * 32 + r;
            float dec = expf(-s * (float)(BLOCK_ - 1 - n));
            ushort4_t k4 = *reinterpret_cast<const ushort4_t*>(kb + (size_t)n * HD_ + d4 * 4);
            ushort4_t v4 = *reinterpret_cast<const ushort4_t*>(vb + (size_t)n * HD_ + d4 * 4);
            float4 kf = { bf2f(k4.x) * dec, bf2f(k4.y) * dec, bf2f(k4.z) * dec, bf2f(k4.w) * dec };
            float4 vf = { bf2f(v4.x), bf2f(v4.y), bf2f(v4.z), bf2f(v4.w) };
            *reinterpret_cast<float4*>(&kt[r][d4 * 4]) = kf;
            *reinterpret_cast<float4*>(&vt[r][d4 * 4]) = vf;
        }
        __syncthreads();
        #pragma unroll
        for (int nn = 0; nn < 32; ++nn) {
            float a[8], b[8];
            #pragma unroll
            for (int i = 0; i < 4; ++i) { a[i] = kt[nn][ty * 4 + i]; a[i + 4] = kt[nn][64 + ty * 4 + i]; }
            #pragma unroll
            for (int j = 0; j < 4; ++j) { b[j] = vt[nn][tx * 4 + j]; b[j + 4] = vt[nn][64 + tx * 4 + j]; }
            #pragma unroll
            for (int i = 0; i < 8; ++i)
                #pragma unroll
                for (int j = 0; j < 8; ++j)
                    acc[i][j] = fmaf(a[i], b[j], acc[i][j]);
        }
    }
    float* out = kvc + (((size_t)bh * NC_ + c) << 14);
    #pragma unroll
    for (int i = 0; i < 8; ++i) {
        int d = (i < 4) ? (ty * 4 + i) : (64 + ty * 4 + i - 4);
        #pragma unroll
        for (int j = 0; j < 8; ++j) {
            int e = (j < 4) ? (tx * 4 + j) : (64 + tx * 4 + j - 4);
            out[(size_t)d * 128 + e] = acc[i][j];
        }
    }
}

// ---------------------------------------------------------------------------
// Prefix scan over chunks: S_0 = 0; S_{c+1} = bd*S_c + KV_c (in place).
// ---------------------------------------------------------------------------
__global__ __launch_bounds__(256)
void kv_scan_kernel(const float* __restrict__ slope, float* __restrict__ kvc)
{
    const int es = blockIdx.x, bh = blockIdx.y;
    const float s = slope[bh & 15];
    const float bd = expf(-s * (float)BLOCK_);
    const int tid = threadIdx.x;
    float st[16];
    #pragma unroll
    for (int i = 0; i < 16; ++i) st[i] = 0.f;
    float* base = kvc + ((size_t)(bh * NC_) << 14);
    for (int c = 0; c < NC_; ++c) {
        float* p = base + ((size_t)c << 14);
        #pragma unroll
        for (int i = 0; i < 16; ++i) {
            int lin = tid + i * 256;
            int off = (lin >> 5) * 128 + es * 32 + (lin & 31);
            float x = p[off];
            p[off] = st[i];
            st[i] = bd * st[i] + x;
        }
    }
}

// ---------------------------------------------------------------------------
// Per-chunk output -> o (f32, B x S x 2048, written into d_out scratch)
// ---------------------------------------------------------------------------
__global__ __launch_bounds__(256)
void attn_out_kernel(const ushort_t* __restrict__ q, const ushort_t* __restrict__ k,
                     const ushort_t* __restrict__ v, const float* __restrict__ kvs,
                     const float* __restrict__ slope, float* __restrict__ o)
{
    const int c = blockIdx.x, bh = blockIdx.y;
    const int h = bh & 15, b = bh >> 4;
    const float s = slope[h];
    const int tid = threadIdx.x, tx = tid & 15, ty = tid >> 4;
    __shared__ __align__(16) float Qp[64][132];
    __shared__ __align__(16) float Tt[64][132];
    __shared__ __align__(16) float Am[64][260];
    const ushort_t* qb = q + ((size_t)bh * S_ + (size_t)c * BLOCK_) * HD_;
    const ushort_t* kb = k + ((size_t)bh * S_ + (size_t)c * BLOCK_) * HD_;
    const ushort_t* vb = v + ((size_t)bh * S_ + (size_t)c * BLOCK_) * HD_;
    const float* Sc = kvs + (((size_t)bh * NC_ + c) << 14);

    for (int p = 0; p < 4; ++p) {
        __syncthreads();
        #pragma unroll
        for (int i = 0; i < 8; ++i) {
            int lin4 = tid + i * 256;
            int r = lin4 >> 5, d4 = lin4 & 31;
            ushort4_t x4 = *reinterpret_cast<const ushort4_t*>(qb + (size_t)(p * 64 + r) * HD_ + d4 * 4);
            float4 xf = { bf2f(x4.x), bf2f(x4.y), bf2f(x4.z), bf2f(x4.w) };
            *reinterpret_cast<float4*>(&Qp[r][d4 * 4]) = xf;
        }
        for (int nt = 0; nt < 4; ++nt) {
            __syncthreads();
            #pragma unroll
            for (int i = 0; i < 8; ++i) {
                int lin4 = tid + i * 256;
                int r = lin4 >> 5, d4 = lin4 & 31;
                ushort4_t x4 = *reinterpret_cast<const ushort4_t*>(kb + (size_t)(nt * 64 + r) * HD_ + d4 * 4);
                float4 xf = { bf2f(x4.x), bf2f(x4.y), bf2f(x4.z), bf2f(x4.w) };
                *reinterpret_cast<float4*>(&Tt[r][d4 * 4]) = xf;
            }
            __syncthreads();
            float pacc[4][4];
            #pragma unroll
            for (int i = 0; i < 4; ++i)
                #pragma unroll
                for (int j = 0; j < 4; ++j) pacc[i][j] = 0.f;
            #pragma unroll 4
            for (int d = 0; d < 128; ++d) {
                float a[4], bb[4];
                #pragma unroll
                for (int i = 0; i < 4; ++i) a[i]  = Qp[ty * 4 + i][d];
                #pragma unroll
                for (int j = 0; j < 4; ++j) bb[j] = Tt[tx * 4 + j][d];
                #pragma unroll
                for (int i = 0; i < 4; ++i)
                    #pragma unroll
                    for (int j = 0; j < 4; ++j)
                        pacc[i][j] = fmaf(a[i], bb[j], pacc[i][j]);
            }
            #pragma unroll
            for (int i = 0; i < 4; ++i) {
                int m = p * 64 + ty * 4 + i;
                #pragma unroll
                for (int j = 0; j < 4; ++j) {
                    int n = nt * 64 + tx * 4 + j;
                    float dec = (m >= n) ? expf(-s * (float)(m - n)) : 0.f;
                    Am[ty * 4 + i][nt * 64 + tx * 4 + j] = pacc[i][j] * dec;
                }
            }
        }
        float oa[4][8], ob[4][8];
        #pragma unroll
        for (int i = 0; i < 4; ++i)
            #pragma unroll
            for (int j = 0; j < 8; ++j) { oa[i][j] = 0.f; ob[i][j] = 0.f; }

        for (int nt = 0; nt < 4; ++nt) {
            __syncthreads();
            #pragma unroll
            for (int i = 0; i < 8; ++i) {
                int lin4 = tid + i * 256;
                int r = lin4 >> 5, d4 = lin4 & 31;
                ushort4_t x4 = *reinterpret_cast<const ushort4_t*>(vb + (size_t)(nt * 64 + r) * HD_ + d4 * 4);
                float4 xf = { bf2f(x4.x), bf2f(x4.y), bf2f(x4.z), bf2f(x4.w) };
                *reinterpret_cast<float4*>(&Tt[r][d4 * 4]) = xf;
            }
            __syncthreads();
            #pragma unroll 4
            for (int n = 0; n < 64; ++n) {
                float a[4], vv[8];
                #pragma unroll
                for (int i = 0; i < 4; ++i) a[i] = Am[ty * 4 + i][nt * 64 + n];
                #pragma unroll
                for (int j = 0; j < 8; ++j)
                    vv[j] = Tt[n][(j < 4) ? (tx * 4 + j) : (64 + tx * 4 + j - 4)];
                #pragma unroll
                for (int i = 0; i < 4; ++i)
                    #pragma unroll
                    for (int j = 0; j < 8; ++j)
                        oa[i][j] = fmaf(a[i], vv[j], oa[i][j]);
            }
        }
        for (int dt = 0; dt < 2; ++dt) {
            __syncthreads();
            #pragma unroll
            for (int i = 0; i < 8; ++i) {
                int lin4 = tid + i * 256;
                int r = lin4 >> 5, d4 = lin4 & 31;
                *reinterpret_cast<float4*>(&Tt[r][d4 * 4]) =
                    *reinterpret_cast<const float4*>(Sc + (size_t)(dt * 64 + r) * 128 + d4 * 4);
            }
            __syncthreads();
            #pragma unroll 4
            for (int dd = 0; dd < 64; ++dd) {
                float a[4], sv[8];
                #pragma unroll
                for (int i = 0; i < 4; ++i) a[i] = Qp[ty * 4 + i][dt * 64 + dd];
                #pragma unroll
                for (int j = 0; j < 8; ++j)
                    sv[j] = Tt[dd][(j < 4) ? (tx * 4 + j) : (64 + tx * 4 + j - 4)];
                #pragma unroll
                for (int i = 0; i < 4; ++i)
                    #pragma unroll
                    for (int j = 0; j < 8; ++j)
                        ob[i][j] = fmaf(a[i], sv[j], ob[i][j]);
            }
        }
        #pragma unroll
        for (int i = 0; i < 4; ++i) {
            int m = p * 64 + ty * 4 + i;
            float qdec = expf(-s * (float)(m + 1));
            float* orow = o + ((size_t)(b * S_ + c * BLOCK_ + m)) * H_ + h * HD_;
            #pragma unroll
            for (int j = 0; j < 8; ++j) {
                int col = (j < 4) ? (tx * 4 + j) : (64 + tx * 4 + j - 4);
                orow[col] = oa[i][j] + qdec * ob[i][j];
            }
        }
    }
}

// ---------------------------------------------------------------------------
// RMSNorm * norm_weight * gate: reads f32 o (d_out scratch), writes bf16 o_n.
// ---------------------------------------------------------------------------
__global__ __launch_bounds__(256)
void norm_gate_kernel(const float* __restrict__ o, const ushort_t* __restrict__ gate,
                      const float* __restrict__ nw, ushort_t* __restrict__ on)
{
    const int row = blockIdx.x;
    const int tid = threadIdx.x;
    const float* orow = o + (size_t)row * H_;
    const ushort_t* grow = gate + (size_t)row * H_;
    ushort_t* onrow = on + (size_t)row * H_;
    float vals[8];
    float ss = 0.f;
    #pragma unroll
    for (int i = 0; i < 8; ++i) {
        vals[i] = orow[tid + i * 256];
        ss += vals[i] * vals[i];
    }
    __shared__ float red[256];
    red[tid] = ss;
    __syncthreads();
    #pragma unroll
    for (int st = 128; st > 0; st >>= 1) {
        if (tid < st) red[tid] += red[tid + st];
        __syncthreads();
    }
    float scale = rsqrtf(red[0] * (1.f / (float)H_) + EPS_);
    #pragma unroll
    for (int i = 0; i < 8; ++i) {
        int cidx = tid + i * 256;
        onrow[cidx] = f2bf(vals[i] * scale * nw[cidx] * bf2f(grow[cidx]));
    }
}

// ---------------------------------------------------------------------------
extern "C" void kernel_launch(void* const* d_in, const int* in_sizes, int n_in,
                              void* d_out, int out_size, void* d_ws, size_t ws_size,
                              hipStream_t stream)
{
    const float* hidden = (const float*)d_in[0];
    const float* mask   = (const float*)d_in[1];
    const float* slope  = (const float*)d_in[2];
    const float* w_qkv  = (const float*)d_in[3];
    const float* w_gate = (const float*)d_in[4];
    const float* w_out  = (const float*)d_in[5];
    const float* nw     = (const float*)d_in[6];

    const size_t MH = (size_t)M_ * H_;                 // 16,777,216 elements
    // region0: hidden bf16, later o_normed bf16 (aliased; hidden dead by then)
    ushort_t* hid_bf  = (ushort_t*)d_ws;
    ushort_t* on_ws   = hid_bf;
    // region1 (MH ushorts = 33.55MB): wqkvT+wgateT -> kv states f32 -> woutT
    ushort_t* wqkvT   = hid_bf + MH;                   // 12,582,912 elems
    ushort_t* wgateT  = wqkvT + (size_t)6144 * 2048;   //  4,194,304 elems
    float*    kv_ws   = (float*)wqkvT;                 //  8,388,608 f32 (alias)
    ushort_t* woutT   = wqkvT;                         //  4,194,304 elems (alias)
    // region2/3
    ushort_t* q_ws    = hid_bf + 2 * MH;
    ushort_t* k_ws    = q_ws + MH;
    ushort_t* v_ws    = k_ws + MH;
    ushort_t* gate_ws = v_ws + MH;
    float*    o_f32   = (float*)d_out;                 // pre-norm o scratch

    dim3 blk(256);
    // prep: cast hidden, transpose+cast weights
    cast_bf16_kernel<<<(MH / 4) / 256, blk, 0, stream>>>(hidden, hid_bf);
    transpose_cast_kernel<<<dim3(6144 / 32, 2048 / 32), blk, 0, stream>>>(w_qkv, wqkvT, 2048, 6144);
    transpose_cast_kernel<<<dim3(2048 / 32, 2048 / 32), blk, 0, stream>>>(w_gate, wgateT, 2048, 2048);
    // 1. qkv = silu(hidden @ w_qkv) -> bf16 q/k/v (head layout), v *= mask
    gemm_mfma<2><<<dim3(6144 / 128, M_ / 128), blk, 0, stream>>>(
        hid_bf, wqkvT, M_, 6144, 2048, nullptr, nullptr, q_ws, k_ws, v_ws, mask);
    // 2. gate = sigmoid(hidden @ w_gate) -> bf16
    gemm_mfma<1><<<dim3(2048 / 128, M_ / 128), blk, 0, stream>>>(
        hid_bf, wgateT, M_, 2048, 2048, nullptr, gate_ws, nullptr, nullptr, nullptr, nullptr);
    // 3. per-chunk KV contributions (f32; overwrites wqkvT/wgateT region)
    kv_chunk_kernel<<<dim3(NC_, B_ * NH_), blk, 0, stream>>>(k_ws, v_ws, slope, kv_ws);
    // 4. prefix scan of KV states (in place)
    kv_scan_kernel<<<dim3(4, B_ * NH_), blk, 0, stream>>>(slope, kv_ws);
    // 5. attention outputs -> f32 o into d_out (scratch)
    attn_out_kernel<<<dim3(NC_, B_ * NH_), blk, 0, stream>>>(q_ws, k_ws, v_ws, kv_ws, slope, o_f32);
    // prep final weight (overwrites kv region; kv dead after step 5)
    transpose_cast_kernel<<<dim3(2048 / 32, 2048 / 32), blk, 0, stream>>>(w_out, woutT, 2048, 2048);
    // 6. RMSNorm * nw * gate -> bf16 o_n (overwrites hidden_bf16; dead)
    norm_gate_kernel<<<M_, blk, 0, stream>>>(o_f32, gate_ws, nw, on_ws);
    // 7. out = o_n @ w_out (overwrites d_out)
    gemm_mfma<0><<<dim3(2048 / 128, M_ / 128), blk, 0, stream>>>(
        on_ws, woutT, M_, 2048, 2048, (float*)d_out, nullptr, nullptr, nullptr, nullptr, nullptr);
}

// Round 5
// 655.314 us; speedup vs baseline: 6.8503x; 1.7782x over previous
//
#include <hip/hip_runtime.h>
#include <cstdint>

#define B_ 2
#define S_ 4096
#define H_ 2048
#define NH_ 16
#define HD_ 128
#define BLOCK_ 256
#define NC_ (S_/BLOCK_)   // 16
#define M_ (B_*S_)        // 8192
#define EPS_ 1e-5f

typedef unsigned short ushort_t;
typedef unsigned short u16x4 __attribute__((ext_vector_type(4)));
typedef short frag_ab __attribute__((ext_vector_type(8)));   // 8 bf16 (4 VGPRs)
typedef float frag_cd __attribute__((ext_vector_type(4)));   // 4 f32

static __device__ inline float bf2f(ushort_t u) {
    union { unsigned int i; float f; } x;
    x.i = ((unsigned int)u) << 16;
    return x.f;
}
static __device__ inline ushort_t f2bf(float f) {
    union { float f; unsigned int i; } x;
    x.f = f;
    unsigned int r = x.i + 0x7fffu + ((x.i >> 16) & 1u);
    return (ushort_t)(r >> 16);
}

// async global->LDS, 16B per lane; LDS dest is wave-uniform base + lane*16
static __device__ __forceinline__ void gload_lds16(const ushort_t* g, ushort_t* l) {
    __builtin_amdgcn_global_load_lds(
        (__attribute__((address_space(1))) void*)(uintptr_t)g,
        (__attribute__((address_space(3))) void*)l,
        16, 0, 0);
}

// ---------------------------------------------------------------------------
// Prep: f32 -> bf16 elementwise cast (hidden).
// ---------------------------------------------------------------------------
__global__ __launch_bounds__(256)
void cast_bf16_kernel(const float* __restrict__ in, ushort_t* __restrict__ out)
{
    int i = blockIdx.x * 256 + threadIdx.x;
    float4 v = reinterpret_cast<const float4*>(in)[i];
    u16x4 o = { f2bf(v.x), f2bf(v.y), f2bf(v.z), f2bf(v.w) };
    *reinterpret_cast<u16x4*>(&out[(size_t)i * 4]) = o;
}

// ---------------------------------------------------------------------------
// Prep: W[K][N] f32 -> WT[N][K] bf16 (tiled transpose+cast).
// ---------------------------------------------------------------------------
__global__ __launch_bounds__(256)
void transpose_cast_kernel(const float* __restrict__ W, ushort_t* __restrict__ WT,
                           int K, int N)
{
    __shared__ float t[32][33];
    const int kb = blockIdx.y * 32, nb = blockIdx.x * 32;
    const int tx = threadIdx.x & 31, ty = threadIdx.x >> 5;  // 32 x 8
    #pragma unroll
    for (int i = 0; i < 4; ++i)
        t[ty + i * 8][tx] = W[(size_t)(kb + ty + i * 8) * N + nb + tx];
    __syncthreads();
    #pragma unroll
    for (int i = 0; i < 4; ++i)
        WT[(size_t)(nb + ty + i * 8) * K + kb + tx] = f2bf(t[tx][ty + i * 8]);
}

// ---------------------------------------------------------------------------
// MFMA GEMM: A[M][K] bf16 row-major, BT[N][K] bf16 (pre-transposed B).
// 128x128 tile, BK=32, 4 waves (2x2), 16x16x32 bf16 MFMA, 4x4 frags/wave.
// MODE 0: f32 C.  MODE 1: sigmoid -> bf16 C.
// MODE 2: silu -> q (normal), k (normal) + kT[d][n], vT[e][n] (mask applied).
// ---------------------------------------------------------------------------
template<int MODE>
__global__ __launch_bounds__(256)
void gemm_mfma(const ushort_t* __restrict__ A, const ushort_t* __restrict__ BT,
               int M, int N, int K,
               float* __restrict__ Cf, ushort_t* __restrict__ Cb,
               ushort_t* __restrict__ qo, ushort_t* __restrict__ ko,
               ushort_t* __restrict__ kTo, ushort_t* __restrict__ vTo,
               const float* __restrict__ mask)
{
    __shared__ __align__(16) ushort_t As[128 * 32];   // [row][k] 8KB
    __shared__ __align__(16) ushort_t Bs[128 * 32];   // [col][k] 8KB
    const int tid  = threadIdx.x;
    const int lane = tid & 63, wid = tid >> 6;
    const int wr = wid >> 1, wc = wid & 1;            // wave quadrant
    const int l15 = lane & 15, l4 = lane >> 4;
    const int rowBase = blockIdx.y * 128, colBase = blockIdx.x * 128;

    const int srow = tid >> 2;
    const int sk   = (tid & 3) * 8;

    frag_cd acc[4][4];
    #pragma unroll
    for (int m = 0; m < 4; ++m)
        #pragma unroll
        for (int n = 0; n < 4; ++n) acc[m][n] = 0.f;

    for (int kt = 0; kt < K; kt += 32) {
        __syncthreads();
        #pragma unroll
        for (int j = 0; j < 2; ++j) {
            gload_lds16(A  + (size_t)(rowBase + j * 64 + srow) * K + kt + sk,
                        &As[j * 2048 + wid * 512]);
            gload_lds16(BT + (size_t)(colBase + j * 64 + srow) * K + kt + sk,
                        &Bs[j * 2048 + wid * 512]);
        }
        __syncthreads();

        frag_ab af[4], bf[4];
        #pragma unroll
        for (int m = 0; m < 4; ++m)
            af[m] = *reinterpret_cast<const frag_ab*>(&As[(wr * 64 + m * 16 + l15) * 32 + l4 * 8]);
        #pragma unroll
        for (int n = 0; n < 4; ++n)
            bf[n] = *reinterpret_cast<const frag_ab*>(&Bs[(wc * 64 + n * 16 + l15) * 32 + l4 * 8]);
        #pragma unroll
        for (int m = 0; m < 4; ++m)
            #pragma unroll
            for (int n = 0; n < 4; ++n)
                acc[m][n] = __builtin_amdgcn_mfma_f32_16x16x32_bf16(af[m], bf[n], acc[m][n], 0, 0, 0);
    }

    // epilogue: C/D layout col = lane&15, row = (lane>>4)*4 + reg  [m89/m91]
    const int orow0 = rowBase + wr * 64;
    const int ocol0 = colBase + wc * 64;
    if (MODE == 0) {
        #pragma unroll
        for (int m = 0; m < 4; ++m)
            #pragma unroll
            for (int n = 0; n < 4; ++n)
                #pragma unroll
                for (int r = 0; r < 4; ++r) {
                    int row = orow0 + m * 16 + l4 * 4 + r;
                    int col = ocol0 + n * 16 + l15;
                    Cf[(size_t)row * N + col] = acc[m][n][r];
                }
    } else if (MODE == 1) {
        #pragma unroll
        for (int m = 0; m < 4; ++m)
            #pragma unroll
            for (int n = 0; n < 4; ++n)
                #pragma unroll
                for (int r = 0; r < 4; ++r) {
                    int row = orow0 + m * 16 + l4 * 4 + r;
                    int col = ocol0 + n * 16 + l15;
                    float x = acc[m][n][r];
                    Cb[(size_t)row * N + col] = f2bf(1.f / (1.f + __expf(-x)));
                }
    } else {
        const int which = colBase >> 11;          // block-uniform: 0:q 1:k 2:v
        const int h     = (colBase >> 7) & 15;
        #pragma unroll
        for (int m = 0; m < 4; ++m) {
            int row0 = orow0 + m * 16 + l4 * 4;
            int b = row0 >> 12, sr0 = row0 & 4095;
            int bh = b * NH_ + h;
            #pragma unroll
            for (int n = 0; n < 4; ++n) {
                int d = (ocol0 & 127) + n * 16 + l15;
                float sv[4];
                #pragma unroll
                for (int r = 0; r < 4; ++r) {
                    float x = acc[m][n][r];
                    sv[r] = x / (1.f + __expf(-x));   // silu
                }
                if (which == 0) {
                    #pragma unroll
                    for (int r = 0; r < 4; ++r)
                        qo[((size_t)bh * S_ + sr0 + r) * HD_ + d] = f2bf(sv[r]);
                } else if (which == 1) {
                    u16x4 pk;
                    #pragma unroll
                    for (int r = 0; r < 4; ++r) {
                        ushort_t u = f2bf(sv[r]);
                        ko[((size_t)bh * S_ + sr0 + r) * HD_ + d] = u;
                        pk[r] = u;
                    }
                    *reinterpret_cast<u16x4*>(&kTo[((size_t)bh * HD_ + d) * S_ + sr0]) = pk;
                } else {
                    u16x4 pk;
                    #pragma unroll
                    for (int r = 0; r < 4; ++r)
                        pk[r] = f2bf(sv[r] * mask[b * S_ + sr0 + r]);
                    *reinterpret_cast<u16x4*>(&vTo[((size_t)bh * HD_ + d) * S_ + sr0]) = pk;
                }
            }
        }
    }
}

// ---------------------------------------------------------------------------
// Per-chunk KV state contribution, MFMA, computed TRANSPOSED:
//   KV^T[e][d] = sum_n V[n][e] * k[n][d]*exp(-s*(255-n)), output bf16.
// grid (NC_, B_*NH_), 256 thr (4 waves, each 32 e-rows).
// ---------------------------------------------------------------------------
__global__ __launch_bounds__(256)
void kv_chunk_mfma(const ushort_t* __restrict__ kT, const ushort_t* __restrict__ vT,
                   const float* __restrict__ slope, ushort_t* __restrict__ kvT)
{
    const int c = blockIdx.x, bh = blockIdx.y;
    const float s = slope[bh & 15];
    const int tid = threadIdx.x, lane = tid & 63, w = tid >> 6;
    const int l15 = lane & 15, l4 = lane >> 4;
    __shared__ float dec[BLOCK_];
    __shared__ __align__(16) ushort_t VTl[128 * 64];  // [e][n] swz, 16KB
    __shared__ __align__(16) ushort_t KTl[128 * 64];  // [d][n] swz+decay, 16KB
    dec[tid] = __expf(-s * (float)(BLOCK_ - 1 - tid));

    frag_cd acc[2][8];
    #pragma unroll
    for (int mf = 0; mf < 2; ++mf)
        #pragma unroll
        for (int df = 0; df < 8; ++df) acc[mf][df] = 0.f;

    for (int nt = 0; nt < 4; ++nt) {
        __syncthreads();
        // [128 rows][64 n] tile: 128B/row -> 8 slots/row -> 1024 units
        #pragma unroll
        for (int i = 0; i < 4; ++i) {
            int u = tid + i * 256;            // 0..1023: row=u>>3, slot=u&7
            int row = u >> 3, slot = u & 7;
            size_t gsrc = ((size_t)bh * HD_ + row) * S_ + c * BLOCK_ + nt * 64 + slot * 8;
            frag_ab v8 = *reinterpret_cast<const frag_ab*>(vT + gsrc);
            *reinterpret_cast<frag_ab*>((char*)VTl + row * 128 + ((slot * 16) ^ ((row & 7) << 4))) = v8;
            frag_ab k8 = *reinterpret_cast<const frag_ab*>(kT + gsrc);
            frag_ab kd;
            #pragma unroll
            for (int j = 0; j < 8; ++j)
                kd[j] = (short)f2bf(bf2f((ushort_t)k8[j]) * dec[nt * 64 + slot * 8 + j]);
            *reinterpret_cast<frag_ab*>((char*)KTl + row * 128 + ((slot * 16) ^ ((row & 7) << 4))) = kd;
        }
        __syncthreads();
        #pragma unroll
        for (int ks = 0; ks < 2; ++ks) {
            frag_ab a[2];
            #pragma unroll
            for (int mf = 0; mf < 2; ++mf)
                a[mf] = *reinterpret_cast<const frag_ab*>(
                    (char*)VTl + (w * 32 + mf * 16 + l15) * 128 + ((ks * 64 + l4 * 16) ^ ((l15 & 7) << 4)));
            #pragma unroll
            for (int df = 0; df < 8; ++df) {
                frag_ab bk = *reinterpret_cast<const frag_ab*>(
                    (char*)KTl + (df * 16 + l15) * 128 + ((ks * 64 + l4 * 16) ^ ((l15 & 7) << 4)));
                acc[0][df] = __builtin_amdgcn_mfma_f32_16x16x32_bf16(a[0], bk, acc[0][df], 0, 0, 0);
                acc[1][df] = __builtin_amdgcn_mfma_f32_16x16x32_bf16(a[1], bk, acc[1][df], 0, 0, 0);
            }
        }
    }
    ushort_t* out = kvT + ((size_t)bh * NC_ + c) * 16384;
    #pragma unroll
    for (int mf = 0; mf < 2; ++mf)
        #pragma unroll
        for (int df = 0; df < 8; ++df)
            #pragma unroll
            for (int r = 0; r < 4; ++r) {
                int e = w * 32 + mf * 16 + l4 * 4 + r;
                int d = df * 16 + l15;
                out[e * 128 + d] = f2bf(acc[mf][df][r]);
            }
}

// ---------------------------------------------------------------------------
// Prefix scan over chunks (bf16 in/out, f32 state): ST_c = state BEFORE chunk c.
// ---------------------------------------------------------------------------
__global__ __launch_bounds__(256)
void kv_scan_kernel(const float* __restrict__ slope, const ushort_t* __restrict__ kvT,
                    ushort_t* __restrict__ sT)
{
    const int es = blockIdx.x, bh = blockIdx.y;
    const float s = slope[bh & 15];
    const float bd = __expf(-s * (float)BLOCK_);
    const int tid = threadIdx.x;
    float st[16];
    #pragma unroll
    for (int i = 0; i < 16; ++i) st[i] = 0.f;
    for (int c = 0; c < NC_; ++c) {
        const ushort_t* p = kvT + ((size_t)bh * NC_ + c) * 16384;
        ushort_t* qp = sT + ((size_t)bh * NC_ + c) * 16384;
        #pragma unroll
        for (int i = 0; i < 16; ++i) {
            int lin = tid + i * 256;
            int off = (lin >> 5) * 128 + es * 32 + (lin & 31);
            float x = bf2f(p[off]);
            qp[off] = f2bf(st[i]);
            st[i] = bd * st[i] + x;
        }
    }
}

// ---------------------------------------------------------------------------
// MFMA attention per chunk:
//   o[m][e] = sum_{n<=m} (q[m]@k[n]) e^{-s(m-n)} v[n][e] + e^{-s(m+1)} (q[m]@S^T)[e]
// grid (NC_, B_*NH_), 512 thr (8 waves, each 32 q-rows). Writes o f32 (B,S,2048).
// ---------------------------------------------------------------------------
__global__ __launch_bounds__(512)
void attn_mfma(const ushort_t* __restrict__ q, const ushort_t* __restrict__ k,
               const ushort_t* __restrict__ vT, const ushort_t* __restrict__ sT,
               const float* __restrict__ slope, float* __restrict__ o)
{
    const int c = blockIdx.x, bh = blockIdx.y;
    const int h = bh & 15, b = bh >> 4;
    const float s = slope[h];
    const int tid = threadIdx.x, lane = tid & 63, w = tid >> 6;
    const int l15 = lane & 15, l4 = lane >> 4;

    __shared__ __align__(16) ushort_t SH[16384];   // K[64][128]+VT[128][64] / ST[128][128]
    __shared__ __align__(16) ushort_t P[8][2048];  // per-wave P[32][64] swz

    // Q fragments (A operand), from global
    frag_ab aq[2][4];
    #pragma unroll
    for (int mf = 0; mf < 2; ++mf)
        #pragma unroll
        for (int ks = 0; ks < 4; ++ks) {
            int row = c * BLOCK_ + w * 32 + mf * 16 + l15;
            aq[mf][ks] = *reinterpret_cast<const frag_ab*>(
                q + ((size_t)bh * S_ + row) * HD_ + ks * 32 + l4 * 8);
        }

    frag_cd oa[2][8];
    #pragma unroll
    for (int mf = 0; mf < 2; ++mf)
        #pragma unroll
        for (int ef = 0; ef < 8; ++ef) oa[mf][ef] = 0.f;

    const int wrow = w * 32;
    for (int nt = 0; nt < 4; ++nt) {
        __syncthreads();
        // stage K tile [64][128] at bytes [0,16384): 256B/row, 16 slots/row
        #pragma unroll
        for (int i = 0; i < 2; ++i) {
            int u = tid + i * 512;            // 0..1023: n=u>>4, slot=u&15
            int n = u >> 4, slot = u & 15;
            frag_ab k8 = *reinterpret_cast<const frag_ab*>(
                k + ((size_t)bh * S_ + c * BLOCK_ + nt * 64 + n) * HD_ + slot * 8);
            *reinterpret_cast<frag_ab*>((char*)SH + n * 256 + ((slot * 16) ^ ((n & 7) << 4))) = k8;
        }
        // stage VT tile [128][64] at bytes [16384,32768): 128B/row, 8 slots/row
        #pragma unroll
        for (int i = 0; i < 2; ++i) {
            int u = tid + i * 512;            // 0..1023: e=u>>3, slot=u&7
            int e = u >> 3, slot = u & 7;
            frag_ab v8 = *reinterpret_cast<const frag_ab*>(
                vT + ((size_t)bh * HD_ + e) * S_ + c * BLOCK_ + nt * 64 + slot * 8);
            *reinterpret_cast<frag_ab*>((char*)SH + 16384 + e * 128 + ((slot * 16) ^ ((e & 7) << 4))) = v8;
        }
        __syncthreads();
        if (nt * 64 > wrow + 31) continue;    // tile fully above diagonal

        // ----- QK^T -----
        frag_cd pacc[2][4];
        #pragma unroll
        for (int mf = 0; mf < 2; ++mf)
            #pragma unroll
            for (int nf = 0; nf < 4; ++nf) pacc[mf][nf] = 0.f;
        #pragma unroll
        for (int ks = 0; ks < 4; ++ks)
            #pragma unroll
            for (int nf = 0; nf < 4; ++nf) {
                frag_ab bk = *reinterpret_cast<const frag_ab*>(
                    (char*)SH + (nf * 16 + l15) * 256 + ((ks * 64 + l4 * 16) ^ ((l15 & 7) << 4)));
                pacc[0][nf] = __builtin_amdgcn_mfma_f32_16x16x32_bf16(aq[0][ks], bk, pacc[0][nf], 0, 0, 0);
                pacc[1][nf] = __builtin_amdgcn_mfma_f32_16x16x32_bf16(aq[1][ks], bk, pacc[1][nf], 0, 0, 0);
            }
        // ----- decay + mask -> P (bf16, per-wave LDS, swz ((m&7)<<4)) -----
        #pragma unroll
        for (int mf = 0; mf < 2; ++mf)
            #pragma unroll
            for (int nf = 0; nf < 4; ++nf)
                #pragma unroll
                for (int r = 0; r < 4; ++r) {
                    int m = mf * 16 + l4 * 4 + r;
                    int mrow = wrow + m;
                    int ncol = nt * 64 + nf * 16 + l15;
                    float pv = 0.f;
                    if (mrow >= ncol) pv = pacc[mf][nf][r] * __expf(s * (float)(ncol - mrow));
                    *reinterpret_cast<ushort_t*>(
                        (char*)&P[w][0] + m * 128 + (((nf * 16 + l15) * 2) ^ ((m & 7) << 4))) = f2bf(pv);
                }
        __builtin_amdgcn_sched_barrier(0);
        // ----- PV -----
        #pragma unroll
        for (int ks = 0; ks < 2; ++ks) {
            frag_ab ap[2];
            #pragma unroll
            for (int mf = 0; mf < 2; ++mf)
                ap[mf] = *reinterpret_cast<const frag_ab*>(
                    (char*)&P[w][0] + (mf * 16 + l15) * 128 + ((ks * 64 + l4 * 16) ^ ((l15 & 7) << 4)));
            #pragma unroll
            for (int ef = 0; ef < 8; ++ef) {
                frag_ab bv = *reinterpret_cast<const frag_ab*>(
                    (char*)SH + 16384 + (ef * 16 + l15) * 128 + ((ks * 64 + l4 * 16) ^ ((l15 & 7) << 4)));
                oa[0][ef] = __builtin_amdgcn_mfma_f32_16x16x32_bf16(ap[0], bv, oa[0][ef], 0, 0, 0);
                oa[1][ef] = __builtin_amdgcn_mfma_f32_16x16x32_bf16(ap[1], bv, oa[1][ef], 0, 0, 0);
            }
        }
    }

    // ----- Q@S^T phase -----
    __syncthreads();
    #pragma unroll
    for (int i = 0; i < 4; ++i) {
        int u = tid + i * 512;                // 0..2047: e=u>>4, slot=u&15
        int e = u >> 4, slot = u & 15;
        frag_ab s8 = *reinterpret_cast<const frag_ab*>(
            sT + ((size_t)(bh * NC_ + c)) * 16384 + e * 128 + slot * 8);
        *reinterpret_cast<frag_ab*>((char*)SH + e * 256 + ((slot * 16) ^ ((e & 7) << 4))) = s8;
    }
    __syncthreads();
    // scale Q by qdec = exp(-s*(row+1))
    #pragma unroll
    for (int mf = 0; mf < 2; ++mf) {
        float qd = __expf(-s * (float)(wrow + mf * 16 + l15 + 1));
        #pragma unroll
        for (int ks = 0; ks < 4; ++ks) {
            frag_ab v = aq[mf][ks];
            #pragma unroll
            for (int j = 0; j < 8; ++j)
                v[j] = (short)f2bf(bf2f((ushort_t)v[j]) * qd);
            aq[mf][ks] = v;
        }
    }
    #pragma unroll
    for (int ks = 0; ks < 4; ++ks)
        #pragma unroll
        for (int ef = 0; ef < 8; ++ef) {
            frag_ab bs = *reinterpret_cast<const frag_ab*>(
                (char*)SH + (ef * 16 + l15) * 256 + ((ks * 64 + l4 * 16) ^ ((l15 & 7) << 4)));
            oa[0][ef] = __builtin_amdgcn_mfma_f32_16x16x32_bf16(aq[0][ks], bs, oa[0][ef], 0, 0, 0);
            oa[1][ef] = __builtin_amdgcn_mfma_f32_16x16x32_bf16(aq[1][ks], bs, oa[1][ef], 0, 0, 0);
        }
    // epilogue -> o (B,S,2048) f32
    #pragma unroll
    for (int mf = 0; mf < 2; ++mf)
        #pragma unroll
        for (int ef = 0; ef < 8; ++ef)
            #pragma unroll
            for (int r = 0; r < 4; ++r) {
                int row = c * BLOCK_ + wrow + mf * 16 + l4 * 4 + r;
                int col = h * HD_ + ef * 16 + l15;
                o[((size_t)(b * S_ + row)) * H_ + col] = oa[mf][ef][r];
            }
}

// ---------------------------------------------------------------------------
// RMSNorm * norm_weight * gate: reads f32 o (d_out scratch), writes bf16 o_n.
// ---------------------------------------------------------------------------
__global__ __launch_bounds__(256)
void norm_gate_kernel(const float* __restrict__ o, const ushort_t* __restrict__ gate,
                      const float* __restrict__ nw, ushort_t* __restrict__ on)
{
    const int row = blockIdx.x;
    const int tid = threadIdx.x;
    const float* orow = o + (size_t)row * H_;
    const ushort_t* grow = gate + (size_t)row * H_;
    ushort_t* onrow = on + (size_t)row * H_;
    float vals[8];
    float ss = 0.f;
    #pragma unroll
    for (int i = 0; i < 8; ++i) {
        vals[i] = orow[tid + i * 256];
        ss += vals[i] * vals[i];
    }
    __shared__ float red[256];
    red[tid] = ss;
    __syncthreads();
    #pragma unroll
    for (int st = 128; st > 0; st >>= 1) {
        if (tid < st) red[tid] += red[tid + st];
        __syncthreads();
    }
    float scale = rsqrtf(red[0] * (1.f / (float)H_) + EPS_);
    #pragma unroll
    for (int i = 0; i < 8; ++i) {
        int cidx = tid + i * 256;
        onrow[cidx] = f2bf(vals[i] * scale * nw[cidx] * bf2f(grow[cidx]));
    }
}

// ---------------------------------------------------------------------------
extern "C" void kernel_launch(void* const* d_in, const int* in_sizes, int n_in,
                              void* d_out, int out_size, void* d_ws, size_t ws_size,
                              hipStream_t stream)
{
    const float* hidden = (const float*)d_in[0];
    const float* mask   = (const float*)d_in[1];
    const float* slope  = (const float*)d_in[2];
    const float* w_qkv  = (const float*)d_in[3];
    const float* w_gate = (const float*)d_in[4];
    const float* w_out  = (const float*)d_in[5];
    const float* nw     = (const float*)d_in[6];

    const size_t MH = (size_t)M_ * H_;                 // 16,777,216 elements
    // r0: hidden bf16 -> later o_normed bf16
    ushort_t* hid_bf  = (ushort_t*)d_ws;
    ushort_t* on_ws   = hid_bf;
    // r1: wqkvT+wgateT -> { kvT bf16 | sT bf16 } -> woutT
    ushort_t* wqkvT   = hid_bf + MH;
    ushort_t* wgateT  = wqkvT + (size_t)6144 * 2048;
    ushort_t* kvT_ws  = wqkvT;                         // 8,388,608 elems
    ushort_t* sT_ws   = wqkvT + MH / 2;                // 8,388,608 elems
    ushort_t* woutT   = wqkvT;
    // r2..r5
    ushort_t* q_ws    = hid_bf + 2 * MH;
    ushort_t* k_ws    = q_ws + MH;
    ushort_t* vT_ws   = k_ws + MH;
    ushort_t* gate_ws = vT_ws + MH;
    // kT lives in d_out's first half (dead before attn overwrites d_out)
    ushort_t* kT_ws   = (ushort_t*)d_out;
    float*    o_f32   = (float*)d_out;

    dim3 blk(256);
    cast_bf16_kernel<<<(MH / 4) / 256, blk, 0, stream>>>(hidden, hid_bf);
    transpose_cast_kernel<<<dim3(6144 / 32, 2048 / 32), blk, 0, stream>>>(w_qkv, wqkvT, 2048, 6144);
    transpose_cast_kernel<<<dim3(2048 / 32, 2048 / 32), blk, 0, stream>>>(w_gate, wgateT, 2048, 2048);
    // 1. qkv = silu(hidden @ w_qkv) -> q, k, kT, vT (masked)
    gemm_mfma<2><<<dim3(6144 / 128, M_ / 128), blk, 0, stream>>>(
        hid_bf, wqkvT, M_, 6144, 2048, nullptr, nullptr, q_ws, k_ws, kT_ws, vT_ws, mask);
    // 2. gate = sigmoid(hidden @ w_gate)
    gemm_mfma<1><<<dim3(2048 / 128, M_ / 128), blk, 0, stream>>>(
        hid_bf, wgateT, M_, 2048, 2048, nullptr, gate_ws, nullptr, nullptr, nullptr, nullptr, nullptr);
    // 3. per-chunk KV^T contributions (bf16)
    kv_chunk_mfma<<<dim3(NC_, B_ * NH_), blk, 0, stream>>>(kT_ws, vT_ws, slope, kvT_ws);
    // 4. prefix scan -> S^T bf16 per chunk
    kv_scan_kernel<<<dim3(4, B_ * NH_), blk, 0, stream>>>(slope, kvT_ws, sT_ws);
    // 5. attention -> o f32 into d_out
    attn_mfma<<<dim3(NC_, B_ * NH_), dim3(512), 0, stream>>>(
        q_ws, k_ws, vT_ws, sT_ws, slope, o_f32);
    // prep final weight (kvT dead; sT untouched)
    transpose_cast_kernel<<<dim3(2048 / 32, 2048 / 32), blk, 0, stream>>>(w_out, woutT, 2048, 2048);
    // 6. RMSNorm * nw * gate -> bf16 o_n (overwrites hidden_bf16; dead)
    norm_gate_kernel<<<M_, blk, 0, stream>>>(o_f32, gate_ws, nw, on_ws);
    // 7. out = o_n @ w_out
    gemm_mfma<0><<<dim3(2048 / 128, M_ / 128), blk, 0, stream>>>(
        on_ws, woutT, M_, 2048, 2048, (float*)d_out, nullptr, nullptr, nullptr, nullptr, nullptr, nullptr);
}

// Round 7
// 561.917 us; speedup vs baseline: 7.9889x; 1.1662x over previous
//
#include <hip/hip_runtime.h>
#include <cstdint>

#define B_ 2
#define S_ 4096
#define H_ 2048
#define NH_ 16
#define HD_ 128
#define BLOCK_ 256
#define NC_ (S_/BLOCK_)   // 16
#define M_ (B_*S_)        // 8192
#define EPS_ 1e-5f

typedef unsigned short ushort_t;
typedef unsigned short u16x4 __attribute__((ext_vector_type(4)));
typedef short frag_ab __attribute__((ext_vector_type(8)));   // 8 bf16 (4 VGPRs)
typedef float frag_cd __attribute__((ext_vector_type(4)));   // 4 f32

static __device__ inline float bf2f(ushort_t u) {
    union { unsigned int i; float f; } x;
    x.i = ((unsigned int)u) << 16;
    return x.f;
}
static __device__ inline ushort_t f2bf(float f) {
    union { float f; unsigned int i; } x;
    x.f = f;
    unsigned int r = x.i + 0x7fffu + ((x.i >> 16) & 1u);
    return (ushort_t)(r >> 16);
}

// async global->LDS, 16B per lane; LDS dest is wave-uniform base + lane*16
static __device__ __forceinline__ void gload_lds16(const ushort_t* g, ushort_t* l) {
    __builtin_amdgcn_global_load_lds(
        (__attribute__((address_space(1))) void*)(uintptr_t)g,
        (__attribute__((address_space(3))) void*)l,
        16, 0, 0);
}

#define FENCE_ asm volatile("" ::: "memory")
#define LGKM0_ asm volatile("s_waitcnt lgkmcnt(0)" ::: "memory")
#define VMW2_  asm volatile("s_waitcnt vmcnt(2)" ::: "memory")
#define VMW4_  asm volatile("s_waitcnt vmcnt(4)" ::: "memory")
#define VMW0_  asm volatile("s_waitcnt vmcnt(0)" ::: "memory")

// ---------------------------------------------------------------------------
// Prep: f32 -> bf16 elementwise cast (hidden).
// ---------------------------------------------------------------------------
__global__ __launch_bounds__(256)
void cast_bf16_kernel(const float* __restrict__ in, ushort_t* __restrict__ out)
{
    int i = blockIdx.x * 256 + threadIdx.x;
    float4 v = reinterpret_cast<const float4*>(in)[i];
    u16x4 o = { f2bf(v.x), f2bf(v.y), f2bf(v.z), f2bf(v.w) };
    *reinterpret_cast<u16x4*>(&out[(size_t)i * 4]) = o;
}

// ---------------------------------------------------------------------------
// Prep: W[K][N] f32 -> WT[N][K] bf16 (tiled transpose+cast).
// ---------------------------------------------------------------------------
__global__ __launch_bounds__(256)
void transpose_cast_kernel(const float* __restrict__ W, ushort_t* __restrict__ WT,
                           int K, int N)
{
    __shared__ float t[32][33];
    const int kb = blockIdx.y * 32, nb = blockIdx.x * 32;
    const int tx = threadIdx.x & 31, ty = threadIdx.x >> 5;  // 32 x 8
    #pragma unroll
    for (int i = 0; i < 4; ++i)
        t[ty + i * 8][tx] = W[(size_t)(kb + ty + i * 8) * N + nb + tx];
    __syncthreads();
    #pragma unroll
    for (int i = 0; i < 4; ++i)
        WT[(size_t)(nb + ty + i * 8) * K + kb + tx] = f2bf(t[tx][ty + i * 8]);
}

// ---------------------------------------------------------------------------
// 256x256 4-phase MFMA GEMM (T2 swizzle + T3/T4 counted vmcnt + T5 setprio).
// A[M][K] bf16 row-major, BT[N][K] bf16. BK=64, 512 thr = 8 waves (2Mx4N).
// Staging order/iter: B0,B1 | B2,B3 | A0,A2 | A1,A3 (2 gload_lds / phase).
// vmcnt discipline (per-wave counts; drained one barrier BEFORE consumption):
//   ph4: after STG A1,A3(t+1): vmcnt(2) -> barrier   (ph1/ph2 of t+1 read B*,A0,A2)
//   ph2: after STG B2,B3(t+2): vmcnt(4) -> barrier   (ph3 of t+1 reads A1,A3)
//        last iter: vmcnt(0).
//   prologue: stage 8, vmcnt(2), barrier.
// ---------------------------------------------------------------------------
template<int MODE>
__global__ __launch_bounds__(512, 2)
void gemm256(const ushort_t* __restrict__ A, const ushort_t* __restrict__ BT,
             int M, int N, int K,
             float* __restrict__ Cf,
             ushort_t* __restrict__ qo, ushort_t* __restrict__ ko,
             ushort_t* __restrict__ kTo, ushort_t* __restrict__ vTo,
             ushort_t* __restrict__ gateo, const float* __restrict__ mask)
{
    __shared__ __align__(16) ushort_t LA[2][16384];   // 2 x 32KB  [256 rows][64 k]
    __shared__ __align__(16) ushort_t LB[2][16384];   // 2 x 32KB

    const int tid  = threadIdx.x;
    const int lane = tid & 63, wid = tid >> 6;
    const int wm = wid >> 2, wn = wid & 3;
    const int l15 = lane & 15, l4 = lane >> 4;
    const int trow = tid >> 3;                 // staging row within 64-row half
    const int xk   = (tid & 7) ^ (trow & 7);   // inverse-swizzled k-slot

    // XCD-aware bijective swizzle (gridDim.x % 8 == 0 by launch config)
    const int nwg = gridDim.x;
    const int lin = blockIdx.x;
    const int virt = (lin & 7) * (nwg >> 3) + (lin >> 3);
    const int NBX = N >> 8;
    const int by = virt / NBX, bx = virt - by * NBX;
    const int rowBase = by * 256, colBase = bx * 256;

    frag_cd acc[8][4];
    #pragma unroll
    for (int m = 0; m < 8; ++m)
        #pragma unroll
        for (int n = 0; n < 4; ++n) acc[m][n] = 0.f;

    frag_ab fa[4][2];      // current mh's A frags [mi][ks]
    frag_ab fb[2][2][2];   // B frags [nh][ni][ks]

    // swizzled frag read: row stride 128B, 8 x 16B slots, slot ^= row&7
    #define RDF(Lp, row_, sl_) \
        (*reinterpret_cast<const frag_ab*>( \
            reinterpret_cast<const char*>(Lp) + (row_) * 128 + ((((sl_) ^ ((row_) & 7)) & 7) << 4)))
    // stage one 64-row half-tile
    #define STG(Gp, base_, i_, kt_, Lp) \
        gload_lds16((Gp) + (size_t)((base_) + (i_) * 64 + trow) * K + (kt_) + xk * 8, \
                    (Lp) + (i_) * 4096 + wid * 512)

    const int NT = K >> 6;
    int cur = 0;
    // prologue: stage tile 0 in canonical order, drain 6 oldest, barrier
    STG(BT, colBase, 0, 0, LB[0]); STG(BT, colBase, 1, 0, LB[0]);
    STG(BT, colBase, 2, 0, LB[0]); STG(BT, colBase, 3, 0, LB[0]);
    STG(A,  rowBase, 0, 0, LA[0]); STG(A,  rowBase, 2, 0, LA[0]);
    STG(A,  rowBase, 1, 0, LA[0]); STG(A,  rowBase, 3, 0, LA[0]);
    VMW2_; FENCE_; __builtin_amdgcn_s_barrier();

    for (int t = 0; t < NT; ++t) {
        const ushort_t* Ab = LA[cur];
        const ushort_t* Bb = LB[cur];
        ushort_t* An = LA[cur ^ 1];
        ushort_t* Bn = LB[cur ^ 1];
        const int ktn = (t + 1) << 6;
        const bool more = (t + 1) < NT;

        // ---------- phase 1: (mh=0, nh=0) ----------
        #pragma unroll
        for (int mi = 0; mi < 4; ++mi)
            #pragma unroll
            for (int ks = 0; ks < 2; ++ks)
                fa[mi][ks] = RDF(Ab, wm * 128 + mi * 16 + l15, ks * 4 + l4);
        #pragma unroll
        for (int ni = 0; ni < 2; ++ni)
            #pragma unroll
            for (int ks = 0; ks < 2; ++ks)
                fb[0][ni][ks] = RDF(Bb, wn * 64 + ni * 16 + l15, ks * 4 + l4);
        if (more) { STG(BT, colBase, 0, ktn, Bn); STG(BT, colBase, 1, ktn, Bn); }
        FENCE_; __builtin_amdgcn_s_barrier(); LGKM0_;
        __builtin_amdgcn_sched_barrier(0);
        __builtin_amdgcn_s_setprio(1);
        #pragma unroll
        for (int mi = 0; mi < 4; ++mi)
            #pragma unroll
            for (int ni = 0; ni < 2; ++ni)
                #pragma unroll
                for (int ks = 0; ks < 2; ++ks)
                    acc[mi][ni] = __builtin_amdgcn_mfma_f32_16x16x32_bf16(
                        fa[mi][ks], fb[0][ni][ks], acc[mi][ni], 0, 0, 0);
        __builtin_amdgcn_s_setprio(0);
        FENCE_; __builtin_amdgcn_s_barrier();

        // ---------- phase 2: (mh=0, nh=1) ----------
        #pragma unroll
        for (int ni = 0; ni < 2; ++ni)
            #pragma unroll
            for (int ks = 0; ks < 2; ++ks)
                fb[1][ni][ks] = RDF(Bb, wn * 64 + 32 + ni * 16 + l15, ks * 4 + l4);
        if (more) { STG(BT, colBase, 2, ktn, Bn); STG(BT, colBase, 3, ktn, Bn); VMW4_; }
        else      { VMW0_; }
        FENCE_; __builtin_amdgcn_s_barrier(); LGKM0_;
        __builtin_amdgcn_sched_barrier(0);
        __builtin_amdgcn_s_setprio(1);
        #pragma unroll
        for (int mi = 0; mi < 4; ++mi)
            #pragma unroll
            for (int ni = 0; ni < 2; ++ni)
                #pragma unroll
                for (int ks = 0; ks < 2; ++ks)
                    acc[mi][2 + ni] = __builtin_amdgcn_mfma_f32_16x16x32_bf16(
                        fa[mi][ks], fb[1][ni][ks], acc[mi][2 + ni], 0, 0, 0);
        __builtin_amdgcn_s_setprio(0);
        FENCE_; __builtin_amdgcn_s_barrier();

        // ---------- phase 3: (mh=1, nh=0) ----------
        #pragma unroll
        for (int mi = 0; mi < 4; ++mi)
            #pragma unroll
            for (int ks = 0; ks < 2; ++ks)
                fa[mi][ks] = RDF(Ab, wm * 128 + 64 + mi * 16 + l15, ks * 4 + l4);
        if (more) { STG(A, rowBase, 0, ktn, An); STG(A, rowBase, 2, ktn, An); }
        FENCE_; __builtin_amdgcn_s_barrier(); LGKM0_;
        __builtin_amdgcn_sched_barrier(0);
        __builtin_amdgcn_s_setprio(1);
        #pragma unroll
        for (int mi = 0; mi < 4; ++mi)
            #pragma unroll
            for (int ni = 0; ni < 2; ++ni)
                #pragma unroll
                for (int ks = 0; ks < 2; ++ks)
                    acc[4 + mi][ni] = __builtin_amdgcn_mfma_f32_16x16x32_bf16(
                        fa[mi][ks], fb[0][ni][ks], acc[4 + mi][ni], 0, 0, 0);
        __builtin_amdgcn_s_setprio(0);
        FENCE_; __builtin_amdgcn_s_barrier();

        // ---------- phase 4: (mh=1, nh=1) ----------
        if (more) { STG(A, rowBase, 1, ktn, An); STG(A, rowBase, 3, ktn, An); VMW2_; }
        FENCE_; __builtin_amdgcn_s_barrier(); LGKM0_;
        __builtin_amdgcn_sched_barrier(0);
        __builtin_amdgcn_s_setprio(1);
        #pragma unroll
        for (int mi = 0; mi < 4; ++mi)
            #pragma unroll
            for (int ni = 0; ni < 2; ++ni)
                #pragma unroll
                for (int ks = 0; ks < 2; ++ks)
                    acc[4 + mi][2 + ni] = __builtin_amdgcn_mfma_f32_16x16x32_bf16(
                        fa[mi][ks], fb[1][ni][ks], acc[4 + mi][2 + ni], 0, 0, 0);
        __builtin_amdgcn_s_setprio(0);
        FENCE_; __builtin_amdgcn_s_barrier();

        cur ^= 1;
    }
    #undef RDF
    #undef STG

    // ---------------- epilogue ----------------
    const int row0 = rowBase + wm * 128;
    const int c0   = colBase + wn * 64;
    if (MODE == 0) {
        #pragma unroll
        for (int m = 0; m < 8; ++m) {
            int mr = (m >> 2) * 64 + (m & 3) * 16;
            #pragma unroll
            for (int n = 0; n < 4; ++n) {
                int nc = (n >> 1) * 32 + (n & 1) * 16;
                #pragma unroll
                for (int r = 0; r < 4; ++r) {
                    int row = row0 + mr + l4 * 4 + r;
                    int col = c0 + nc + l15;
                    Cf[(size_t)row * N + col] = acc[m][n][r];
                }
            }
        }
    } else {
        const int which = c0 >> 11;               // 0:q 1:k 2:v 3:gate
        const int h     = (c0 >> 7) & 15;
        const int d0    = c0 & 127;
        const int b     = row0 >> 12;
        const int bh    = b * NH_ + h;
        #pragma unroll
        for (int m = 0; m < 8; ++m) {
            int mr = (m >> 2) * 64 + (m & 3) * 16;
            int sr0 = (row0 & 4095) + mr + l4 * 4;
            #pragma unroll
            for (int n = 0; n < 4; ++n) {
                int nc = (n >> 1) * 32 + (n & 1) * 16;
                float x0 = acc[m][n][0], x1 = acc[m][n][1];
                float x2 = acc[m][n][2], x3 = acc[m][n][3];
                if (which == 3) {
                    int col_g = (c0 - 6144) + nc + l15;
                    ushort_t* gp = gateo + (size_t)(row0 + mr + l4 * 4) * H_ + col_g;
                    gp[0]       = f2bf(1.f / (1.f + __expf(-x0)));
                    gp[H_]      = f2bf(1.f / (1.f + __expf(-x1)));
                    gp[2 * H_]  = f2bf(1.f / (1.f + __expf(-x2)));
                    gp[3 * H_]  = f2bf(1.f / (1.f + __expf(-x3)));
                } else {
                    int d = d0 + nc + l15;
                    float s0 = x0 / (1.f + __expf(-x0));
                    float s1 = x1 / (1.f + __expf(-x1));
                    float s2 = x2 / (1.f + __expf(-x2));
                    float s3 = x3 / (1.f + __expf(-x3));
                    if (which == 0) {
                        ushort_t* qp = qo + ((size_t)bh * S_ + sr0) * HD_ + d;
                        qp[0]        = f2bf(s0);
                        qp[HD_]      = f2bf(s1);
                        qp[2 * HD_]  = f2bf(s2);
                        qp[3 * HD_]  = f2bf(s3);
                    } else if (which == 1) {
                        u16x4 pk = { f2bf(s0), f2bf(s1), f2bf(s2), f2bf(s3) };
                        ushort_t* kp = ko + ((size_t)bh * S_ + sr0) * HD_ + d;
                        kp[0] = pk[0]; kp[HD_] = pk[1]; kp[2 * HD_] = pk[2]; kp[3 * HD_] = pk[3];
                        *reinterpret_cast<u16x4*>(&kTo[((size_t)bh * HD_ + d) * S_ + sr0]) = pk;
                    } else {
                        float mk0 = mask[b * S_ + sr0],     mk1 = mask[b * S_ + sr0 + 1];
                        float mk2 = mask[b * S_ + sr0 + 2], mk3 = mask[b * S_ + sr0 + 3];
                        u16x4 pk = { f2bf(s0 * mk0), f2bf(s1 * mk1), f2bf(s2 * mk2), f2bf(s3 * mk3) };
                        *reinterpret_cast<u16x4*>(&vTo[((size_t)bh * HD_ + d) * S_ + sr0]) = pk;
                    }
                }
            }
        }
    }
}

// ---------------------------------------------------------------------------
// Per-chunk KV state contribution (MFMA, transposed output) — unchanged.
// ---------------------------------------------------------------------------
__global__ __launch_bounds__(256)
void kv_chunk_mfma(const ushort_t* __restrict__ kT, const ushort_t* __restrict__ vT,
                   const float* __restrict__ slope, ushort_t* __restrict__ kvT)
{
    const int c = blockIdx.x, bh = blockIdx.y;
    const float s = slope[bh & 15];
    const int tid = threadIdx.x, lane = tid & 63, w = tid >> 6;
    const int l15 = lane & 15, l4 = lane >> 4;
    __shared__ float dec[BLOCK_];
    __shared__ __align__(16) ushort_t VTl[128 * 64];
    __shared__ __align__(16) ushort_t KTl[128 * 64];
    dec[tid] = __expf(-s * (float)(BLOCK_ - 1 - tid));

    frag_cd acc[2][8];
    #pragma unroll
    for (int mf = 0; mf < 2; ++mf)
        #pragma unroll
        for (int df = 0; df < 8; ++df) acc[mf][df] = 0.f;

    for (int nt = 0; nt < 4; ++nt) {
        __syncthreads();
        #pragma unroll
        for (int i = 0; i < 4; ++i) {
            int u = tid + i * 256;
            int row = u >> 3, slot = u & 7;
            size_t gsrc = ((size_t)bh * HD_ + row) * S_ + c * BLOCK_ + nt * 64 + slot * 8;
            frag_ab v8 = *reinterpret_cast<const frag_ab*>(vT + gsrc);
            *reinterpret_cast<frag_ab*>((char*)VTl + row * 128 + ((slot * 16) ^ ((row & 7) << 4))) = v8;
            frag_ab k8 = *reinterpret_cast<const frag_ab*>(kT + gsrc);
            frag_ab kd;
            #pragma unroll
            for (int j = 0; j < 8; ++j)
                kd[j] = (short)f2bf(bf2f((ushort_t)k8[j]) * dec[nt * 64 + slot * 8 + j]);
            *reinterpret_cast<frag_ab*>((char*)KTl + row * 128 + ((slot * 16) ^ ((row & 7) << 4))) = kd;
        }
        __syncthreads();
        #pragma unroll
        for (int ks = 0; ks < 2; ++ks) {
            frag_ab a[2];
            #pragma unroll
            for (int mf = 0; mf < 2; ++mf)
                a[mf] = *reinterpret_cast<const frag_ab*>(
                    (char*)VTl + (w * 32 + mf * 16 + l15) * 128 + ((ks * 64 + l4 * 16) ^ ((l15 & 7) << 4)));
            #pragma unroll
            for (int df = 0; df < 8; ++df) {
                frag_ab bk = *reinterpret_cast<const frag_ab*>(
                    (char*)KTl + (df * 16 + l15) * 128 + ((ks * 64 + l4 * 16) ^ ((l15 & 7) << 4)));
                acc[0][df] = __builtin_amdgcn_mfma_f32_16x16x32_bf16(a[0], bk, acc[0][df], 0, 0, 0);
                acc[1][df] = __builtin_amdgcn_mfma_f32_16x16x32_bf16(a[1], bk, acc[1][df], 0, 0, 0);
            }
        }
    }
    ushort_t* out = kvT + ((size_t)bh * NC_ + c) * 16384;
    #pragma unroll
    for (int mf = 0; mf < 2; ++mf)
        #pragma unroll
        for (int df = 0; df < 8; ++df)
            #pragma unroll
            for (int r = 0; r < 4; ++r) {
                int e = w * 32 + mf * 16 + l4 * 4 + r;
                int d = df * 16 + l15;
                out[e * 128 + d] = f2bf(acc[mf][df][r]);
            }
}

// ---------------------------------------------------------------------------
// Prefix scan over chunks — unchanged.
// ---------------------------------------------------------------------------
__global__ __launch_bounds__(256)
void kv_scan_kernel(const float* __restrict__ slope, const ushort_t* __restrict__ kvT,
                    ushort_t* __restrict__ sT)
{
    const int es = blockIdx.x, bh = blockIdx.y;
    const float s = slope[bh & 15];
    const float bd = __expf(-s * (float)BLOCK_);
    const int tid = threadIdx.x;
    float st[16];
    #pragma unroll
    for (int i = 0; i < 16; ++i) st[i] = 0.f;
    for (int c = 0; c < NC_; ++c) {
        const ushort_t* p = kvT + ((size_t)bh * NC_ + c) * 16384;
        ushort_t* qp = sT + ((size_t)bh * NC_ + c) * 16384;
        #pragma unroll
        for (int i = 0; i < 16; ++i) {
            int lin = tid + i * 256;
            int off = (lin >> 5) * 128 + es * 32 + (lin & 31);
            float x = bf2f(p[off]);
            qp[off] = f2bf(st[i]);
            st[i] = bd * st[i] + x;
        }
    }
}

// ---------------------------------------------------------------------------
// MFMA attention per chunk — unchanged.
// ---------------------------------------------------------------------------
__global__ __launch_bounds__(512)
void attn_mfma(const ushort_t* __restrict__ q, const ushort_t* __restrict__ k,
               const ushort_t* __restrict__ vT, const ushort_t* __restrict__ sT,
               const float* __restrict__ slope, float* __restrict__ o)
{
    const int c = blockIdx.x, bh = blockIdx.y;
    const int h = bh & 15, b = bh >> 4;
    const float s = slope[h];
    const int tid = threadIdx.x, lane = tid & 63, w = tid >> 6;
    const int l15 = lane & 15, l4 = lane >> 4;

    __shared__ __align__(16) ushort_t SH[16384];
    __shared__ __align__(16) ushort_t P[8][2048];

    frag_ab aq[2][4];
    #pragma unroll
    for (int mf = 0; mf < 2; ++mf)
        #pragma unroll
        for (int ks = 0; ks < 4; ++ks) {
            int row = c * BLOCK_ + w * 32 + mf * 16 + l15;
            aq[mf][ks] = *reinterpret_cast<const frag_ab*>(
                q + ((size_t)bh * S_ + row) * HD_ + ks * 32 + l4 * 8);
        }

    frag_cd oa[2][8];
    #pragma unroll
    for (int mf = 0; mf < 2; ++mf)
        #pragma unroll
        for (int ef = 0; ef < 8; ++ef) oa[mf][ef] = 0.f;

    const int wrow = w * 32;
    for (int nt = 0; nt < 4; ++nt) {
        __syncthreads();
        #pragma unroll
        for (int i = 0; i < 2; ++i) {
            int u = tid + i * 512;
            int n = u >> 4, slot = u & 15;
            frag_ab k8 = *reinterpret_cast<const frag_ab*>(
                k + ((size_t)bh * S_ + c * BLOCK_ + nt * 64 + n) * HD_ + slot * 8);
            *reinterpret_cast<frag_ab*>((char*)SH + n * 256 + ((slot * 16) ^ ((n & 7) << 4))) = k8;
        }
        #pragma unroll
        for (int i = 0; i < 2; ++i) {
            int u = tid + i * 512;
            int e = u >> 3, slot = u & 7;
            frag_ab v8 = *reinterpret_cast<const frag_ab*>(
                vT + ((size_t)bh * HD_ + e) * S_ + c * BLOCK_ + nt * 64 + slot * 8);
            *reinterpret_cast<frag_ab*>((char*)SH + 16384 + e * 128 + ((slot * 16) ^ ((e & 7) << 4))) = v8;
        }
        __syncthreads();
        if (nt * 64 > wrow + 31) continue;

        frag_cd pacc[2][4];
        #pragma unroll
        for (int mf = 0; mf < 2; ++mf)
            #pragma unroll
            for (int nf = 0; nf < 4; ++nf) pacc[mf][nf] = 0.f;
        #pragma unroll
        for (int ks = 0; ks < 4; ++ks)
            #pragma unroll
            for (int nf = 0; nf < 4; ++nf) {
                frag_ab bk = *reinterpret_cast<const frag_ab*>(
                    (char*)SH + (nf * 16 + l15) * 256 + ((ks * 64 + l4 * 16) ^ ((l15 & 7) << 4)));
                pacc[0][nf] = __builtin_amdgcn_mfma_f32_16x16x32_bf16(aq[0][ks], bk, pacc[0][nf], 0, 0, 0);
                pacc[1][nf] = __builtin_amdgcn_mfma_f32_16x16x32_bf16(aq[1][ks], bk, pacc[1][nf], 0, 0, 0);
            }
        #pragma unroll
        for (int mf = 0; mf < 2; ++mf)
            #pragma unroll
            for (int nf = 0; nf < 4; ++nf)
                #pragma unroll
                for (int r = 0; r < 4; ++r) {
                    int m = mf * 16 + l4 * 4 + r;
                    int mrow = wrow + m;
                    int ncol = nt * 64 + nf * 16 + l15;
                    float pv = 0.f;
                    if (mrow >= ncol) pv = pacc[mf][nf][r] * __expf(s * (float)(ncol - mrow));
                    *reinterpret_cast<ushort_t*>(
                        (char*)&P[w][0] + m * 128 + (((nf * 16 + l15) * 2) ^ ((m & 7) << 4))) = f2bf(pv);
                }
        __builtin_amdgcn_sched_barrier(0);
        #pragma unroll
        for (int ks = 0; ks < 2; ++ks) {
            frag_ab ap[2];
            #pragma unroll
            for (int mf = 0; mf < 2; ++mf)
                ap[mf] = *reinterpret_cast<const frag_ab*>(
                    (char*)&P[w][0] + (mf * 16 + l15) * 128 + ((ks * 64 + l4 * 16) ^ ((l15 & 7) << 4)));
            #pragma unroll
            for (int ef = 0; ef < 8; ++ef) {
                frag_ab bv = *reinterpret_cast<const frag_ab*>(
                    (char*)SH + 16384 + (ef * 16 + l15) * 128 + ((ks * 64 + l4 * 16) ^ ((l15 & 7) << 4)));
                oa[0][ef] = __builtin_amdgcn_mfma_f32_16x16x32_bf16(ap[0], bv, oa[0][ef], 0, 0, 0);
                oa[1][ef] = __builtin_amdgcn_mfma_f32_16x16x32_bf16(ap[1], bv, oa[1][ef], 0, 0, 0);
            }
        }
    }

    __syncthreads();
    #pragma unroll
    for (int i = 0; i < 4; ++i) {
        int u = tid + i * 512;
        int e = u >> 4, slot = u & 15;
        frag_ab s8 = *reinterpret_cast<const frag_ab*>(
            sT + ((size_t)(bh * NC_ + c)) * 16384 + e * 128 + slot * 8);
        *reinterpret_cast<frag_ab*>((char*)SH + e * 256 + ((slot * 16) ^ ((e & 7) << 4))) = s8;
    }
    __syncthreads();
    #pragma unroll
    for (int mf = 0; mf < 2; ++mf) {
        float qd = __expf(-s * (float)(wrow + mf * 16 + l15 + 1));
        #pragma unroll
        for (int ks = 0; ks < 4; ++ks) {
            frag_ab v = aq[mf][ks];
            #pragma unroll
            for (int j = 0; j < 8; ++j)
                v[j] = (short)f2bf(bf2f((ushort_t)v[j]) * qd);
            aq[mf][ks] = v;
        }
    }
    #pragma unroll
    for (int ks = 0; ks < 4; ++ks)
        #pragma unroll
        for (int ef = 0; ef < 8; ++ef) {
            frag_ab bs = *reinterpret_cast<const frag_ab*>(
                (char*)SH + (ef * 16 + l15) * 256 + ((ks * 64 + l4 * 16) ^ ((l15 & 7) << 4)));
            oa[0][ef] = __builtin_amdgcn_mfma_f32_16x16x32_bf16(aq[0][ks], bs, oa[0][ef], 0, 0, 0);
            oa[1][ef] = __builtin_amdgcn_mfma_f32_16x16x32_bf16(aq[1][ks], bs, oa[1][ef], 0, 0, 0);
        }
    #pragma unroll
    for (int mf = 0; mf < 2; ++mf)
        #pragma unroll
        for (int ef = 0; ef < 8; ++ef)
            #pragma unroll
            for (int r = 0; r < 4; ++r) {
                int row = c * BLOCK_ + wrow + mf * 16 + l4 * 4 + r;
                int col = h * HD_ + ef * 16 + l15;
                o[((size_t)(b * S_ + row)) * H_ + col] = oa[mf][ef][r];
            }
}

// ---------------------------------------------------------------------------
// RMSNorm * norm_weight * gate — unchanged.
// ---------------------------------------------------------------------------
__global__ __launch_bounds__(256)
void norm_gate_kernel(const float* __restrict__ o, const ushort_t* __restrict__ gate,
                      const float* __restrict__ nw, ushort_t* __restrict__ on)
{
    const int row = blockIdx.x;
    const int tid = threadIdx.x;
    const float* orow = o + (size_t)row * H_;
    const ushort_t* grow = gate + (size_t)row * H_;
    ushort_t* onrow = on + (size_t)row * H_;
    float vals[8];
    float ss = 0.f;
    #pragma unroll
    for (int i = 0; i < 8; ++i) {
        vals[i] = orow[tid + i * 256];
        ss += vals[i] * vals[i];
    }
    __shared__ float red[256];
    red[tid] = ss;
    __syncthreads();
    #pragma unroll
    for (int st = 128; st > 0; st >>= 1) {
        if (tid < st) red[tid] += red[tid + st];
        __syncthreads();
    }
    float scale = rsqrtf(red[0] * (1.f / (float)H_) + EPS_);
    #pragma unroll
    for (int i = 0; i < 8; ++i) {
        int cidx = tid + i * 256;
        onrow[cidx] = f2bf(vals[i] * scale * nw[cidx] * bf2f(grow[cidx]));
    }
}

// ---------------------------------------------------------------------------
extern "C" void kernel_launch(void* const* d_in, const int* in_sizes, int n_in,
                              void* d_out, int out_size, void* d_ws, size_t ws_size,
                              hipStream_t stream)
{
    const float* hidden = (const float*)d_in[0];
    const float* mask   = (const float*)d_in[1];
    const float* slope  = (const float*)d_in[2];
    const float* w_qkv  = (const float*)d_in[3];
    const float* w_gate = (const float*)d_in[4];
    const float* w_out  = (const float*)d_in[5];
    const float* nw     = (const float*)d_in[6];

    const size_t MH = (size_t)M_ * H_;                 // 16,777,216 elements
    ushort_t* hid_bf  = (ushort_t*)d_ws;
    ushort_t* on_ws   = hid_bf;
    // r1: wqkvT (6144x2048) + wgateT (2048x2048) contiguous = BT[8192][2048]
    ushort_t* wqkvT   = hid_bf + MH;
    ushort_t* wgateT  = wqkvT + (size_t)6144 * 2048;
    ushort_t* kvT_ws  = wqkvT;
    ushort_t* sT_ws   = wqkvT + MH / 2;
    ushort_t* woutT   = wqkvT;
    ushort_t* q_ws    = hid_bf + 2 * MH;
    ushort_t* k_ws    = q_ws + MH;
    ushort_t* vT_ws   = k_ws + MH;
    ushort_t* gate_ws = vT_ws + MH;
    ushort_t* kT_ws   = (ushort_t*)d_out;
    float*    o_f32   = (float*)d_out;

    dim3 blk(256);
    cast_bf16_kernel<<<(MH / 4) / 256, blk, 0, stream>>>(hidden, hid_bf);
    transpose_cast_kernel<<<dim3(6144 / 32, 2048 / 32), blk, 0, stream>>>(w_qkv, wqkvT, 2048, 6144);
    transpose_cast_kernel<<<dim3(2048 / 32, 2048 / 32), blk, 0, stream>>>(w_gate, wgateT, 2048, 2048);
    // 1+2. combined qkv+gate GEMM (N=8192), 256^2 4-phase pipelined
    gemm256<2><<<dim3((M_ / 256) * (8192 / 256)), dim3(512), 0, stream>>>(
        hid_bf, wqkvT, M_, 8192, 2048,
        nullptr, q_ws, k_ws, kT_ws, vT_ws, gate_ws, mask);
    // 3. per-chunk KV^T contributions
    kv_chunk_mfma<<<dim3(NC_, B_ * NH_), blk, 0, stream>>>(kT_ws, vT_ws, slope, kvT_ws);
    // 4. prefix scan -> S^T per chunk
    kv_scan_kernel<<<dim3(4, B_ * NH_), blk, 0, stream>>>(slope, kvT_ws, sT_ws);
    // 5. attention -> o f32 into d_out
    attn_mfma<<<dim3(NC_, B_ * NH_), dim3(512), 0, stream>>>(
        q_ws, k_ws, vT_ws, sT_ws, slope, o_f32);
    // prep final weight (kvT dead; sT untouched)
    transpose_cast_kernel<<<dim3(2048 / 32, 2048 / 32), blk, 0, stream>>>(w_out, woutT, 2048, 2048);
    // 6. RMSNorm * nw * gate -> bf16 o_n
    norm_gate_kernel<<<M_, blk, 0, stream>>>(o_f32, gate_ws, nw, on_ws);
    // 7. out = o_n @ w_out (256^2 4-phase, f32 C)
    gemm256<0><<<dim3((M_ / 256) * (2048 / 256)), dim3(512), 0, stream>>>(
        on_ws, woutT, M_, 2048, 2048,
        (float*)d_out, nullptr, nullptr, nullptr, nullptr, nullptr, nullptr);
}

// Round 8
// 544.415 us; speedup vs baseline: 8.2458x; 1.0321x over previous
//
#include <hip/hip_runtime.h>
#include <cstdint>

#define B_ 2
#define S_ 4096
#define H_ 2048
#define NH_ 16
#define HD_ 128
#define BLOCK_ 256
#define NC_ (S_/BLOCK_)   // 16
#define M_ (B_*S_)        // 8192
#define EPS_ 1e-5f

typedef unsigned short ushort_t;
typedef unsigned short u16x4 __attribute__((ext_vector_type(4)));
typedef short frag_ab __attribute__((ext_vector_type(8)));   // 8 bf16 (4 VGPRs)
typedef float frag_cd __attribute__((ext_vector_type(4)));   // 4 f32

static __device__ inline float bf2f(ushort_t u) {
    union { unsigned int i; float f; } x;
    x.i = ((unsigned int)u) << 16;
    return x.f;
}
static __device__ inline ushort_t f2bf(float f) {
    union { float f; unsigned int i; } x;
    x.f = f;
    unsigned int r = x.i + 0x7fffu + ((x.i >> 16) & 1u);
    return (ushort_t)(r >> 16);
}

// async global->LDS, 16B per lane; LDS dest is wave-uniform base + lane*16
static __device__ __forceinline__ void gload_lds16(const ushort_t* g, ushort_t* l) {
    __builtin_amdgcn_global_load_lds(
        (__attribute__((address_space(1))) void*)(uintptr_t)g,
        (__attribute__((address_space(3))) void*)l,
        16, 0, 0);
}

#define FENCE_ asm volatile("" ::: "memory")
#define VMW2_  asm volatile("s_waitcnt vmcnt(2)" ::: "memory")
#define VMW4_  asm volatile("s_waitcnt vmcnt(4)" ::: "memory")
#define VMW0_  asm volatile("s_waitcnt vmcnt(0)" ::: "memory")

// ---------------------------------------------------------------------------
// Prep: f32 -> bf16 elementwise cast (hidden).
// ---------------------------------------------------------------------------
__global__ __launch_bounds__(256)
void cast_bf16_kernel(const float* __restrict__ in, ushort_t* __restrict__ out)
{
    int i = blockIdx.x * 256 + threadIdx.x;
    float4 v = reinterpret_cast<const float4*>(in)[i];
    u16x4 o = { f2bf(v.x), f2bf(v.y), f2bf(v.z), f2bf(v.w) };
    *reinterpret_cast<u16x4*>(&out[(size_t)i * 4]) = o;
}

// ---------------------------------------------------------------------------
// Prep: W[K][N] f32 -> WT[N][K] bf16 (tiled transpose+cast).
// ---------------------------------------------------------------------------
__global__ __launch_bounds__(256)
void transpose_cast_kernel(const float* __restrict__ W, ushort_t* __restrict__ WT,
                           int K, int N)
{
    __shared__ float t[32][33];
    const int kb = blockIdx.y * 32, nb = blockIdx.x * 32;
    const int tx = threadIdx.x & 31, ty = threadIdx.x >> 5;  // 32 x 8
    #pragma unroll
    for (int i = 0; i < 4; ++i)
        t[ty + i * 8][tx] = W[(size_t)(kb + ty + i * 8) * N + nb + tx];
    __syncthreads();
    #pragma unroll
    for (int i = 0; i < 4; ++i)
        WT[(size_t)(nb + ty + i * 8) * K + kb + tx] = f2bf(t[tx][ty + i * 8]);
}

// ---------------------------------------------------------------------------
// 256x256 MFMA GEMM, 4 MFMA clusters + 2 barriers per K-tile.
// A[M][K] bf16 row-major, BT[N][K] bf16. BK=64, 512 thr = 8 waves (2Mx4N).
// Staging order/iter: B0,B1 | B2,B3 | A0,A2 | A1,A3 (2 gload_lds / cluster).
// Sync invariants (per-wave vmcnt; cross-wave visibility = drain + barrier):
//   loop top (post end-barrier of t-1): B0-3(t), A0(t), A2(t) visible;
//     A1,A3(t) in flight (2 outstanding).
//   C2 end: vmcnt(4) drains A1,A3(t) [leaves 4 B(t+1)] -> MID barrier
//     -> C3's fa1 reads (A1/A3 rows) safe.  Last iter: vmcnt(0).
//   C4 end: vmcnt(2) drains B0-3,A0,A2(t+1) [leaves A1,A3(t+1)] -> END barrier.
//   Every cluster's ds_reads are lgkm-consumed by its MFMAs before the wave
//   reaches the next barrier -> staging can never WAR a live reader.
// ds_reads issue under the neighboring MFMA cluster (compiler fine-grained
// lgkmcnt) -> LDS pipe overlaps MFMA pipe instead of strict alternation.
// ---------------------------------------------------------------------------
template<int MODE>
__global__ __launch_bounds__(512, 2)
void gemm256(const ushort_t* __restrict__ A, const ushort_t* __restrict__ BT,
             int M, int N, int K,
             float* __restrict__ Cf,
             ushort_t* __restrict__ qo, ushort_t* __restrict__ ko,
             ushort_t* __restrict__ kTo, ushort_t* __restrict__ vTo,
             ushort_t* __restrict__ gateo, const float* __restrict__ mask)
{
    __shared__ __align__(16) ushort_t LA[2][16384];   // 2 x 32KB  [256 rows][64 k]
    __shared__ __align__(16) ushort_t LB[2][16384];   // 2 x 32KB

    const int tid  = threadIdx.x;
    const int lane = tid & 63, wid = tid >> 6;
    const int wm = wid >> 2, wn = wid & 3;
    const int l15 = lane & 15, l4 = lane >> 4;
    const int trow = tid >> 3;                 // staging row within 64-row half
    const int xk   = (tid & 7) ^ (trow & 7);   // inverse-swizzled k-slot

    // XCD-aware bijective swizzle (gridDim.x % 8 == 0 by launch config)
    const int nwg = gridDim.x;
    const int lin = blockIdx.x;
    const int virt = (lin & 7) * (nwg >> 3) + (lin >> 3);
    const int NBX = N >> 8;
    const int by = virt / NBX, bx = virt - by * NBX;
    const int rowBase = by * 256, colBase = bx * 256;

    frag_cd acc[8][4];
    #pragma unroll
    for (int m = 0; m < 8; ++m)
        #pragma unroll
        for (int n = 0; n < 4; ++n) acc[m][n] = 0.f;

    frag_ab fa[4][2];      // current mh's A frags [mi][ks]
    frag_ab fb[2][2][2];   // B frags [nh][ni][ks]

    // swizzled frag read: row stride 128B, 8 x 16B slots, slot ^= row&7
    #define RDF(Lp, row_, sl_) \
        (*reinterpret_cast<const frag_ab*>( \
            reinterpret_cast<const char*>(Lp) + (row_) * 128 + ((((sl_) ^ ((row_) & 7)) & 7) << 4)))
    // stage one 64-row half-tile
    #define STG(Gp, base_, i_, kt_, Lp) \
        gload_lds16((Gp) + (size_t)((base_) + (i_) * 64 + trow) * K + (kt_) + xk * 8, \
                    (Lp) + (i_) * 4096 + wid * 512)

    const int NT = K >> 6;
    int cur = 0;
    // prologue: stage tile 0 in canonical order, drain 6 oldest, barrier
    STG(BT, colBase, 0, 0, LB[0]); STG(BT, colBase, 1, 0, LB[0]);
    STG(BT, colBase, 2, 0, LB[0]); STG(BT, colBase, 3, 0, LB[0]);
    STG(A,  rowBase, 0, 0, LA[0]); STG(A,  rowBase, 2, 0, LA[0]);
    STG(A,  rowBase, 1, 0, LA[0]); STG(A,  rowBase, 3, 0, LA[0]);
    VMW2_; FENCE_; __builtin_amdgcn_s_barrier();
    __builtin_amdgcn_sched_barrier(0);

    for (int t = 0; t < NT; ++t) {
        const ushort_t* Ab = LA[cur];
        const ushort_t* Bb = LB[cur];
        ushort_t* An = LA[cur ^ 1];
        ushort_t* Bn = LB[cur ^ 1];
        const int ktn = (t + 1) << 6;
        const bool more = (t + 1) < NT;

        // ---- C1: read fa0+fb0, stage B0,B1(t+1), MFMA top-left ----
        #pragma unroll
        for (int mi = 0; mi < 4; ++mi)
            #pragma unroll
            for (int ks = 0; ks < 2; ++ks)
                fa[mi][ks] = RDF(Ab, wm * 128 + mi * 16 + l15, ks * 4 + l4);
        #pragma unroll
        for (int ni = 0; ni < 2; ++ni)
            #pragma unroll
            for (int ks = 0; ks < 2; ++ks)
                fb[0][ni][ks] = RDF(Bb, wn * 64 + ni * 16 + l15, ks * 4 + l4);
        if (more) { STG(BT, colBase, 0, ktn, Bn); STG(BT, colBase, 1, ktn, Bn); }
        __builtin_amdgcn_s_setprio(1);
        #pragma unroll
        for (int mi = 0; mi < 4; ++mi)
            #pragma unroll
            for (int ni = 0; ni < 2; ++ni)
                #pragma unroll
                for (int ks = 0; ks < 2; ++ks)
                    acc[mi][ni] = __builtin_amdgcn_mfma_f32_16x16x32_bf16(
                        fa[mi][ks], fb[0][ni][ks], acc[mi][ni], 0, 0, 0);
        __builtin_amdgcn_s_setprio(0);

        // ---- C2: read fb1, stage B2,B3(t+1), MFMA top-right; mid sync ----
        #pragma unroll
        for (int ni = 0; ni < 2; ++ni)
            #pragma unroll
            for (int ks = 0; ks < 2; ++ks)
                fb[1][ni][ks] = RDF(Bb, wn * 64 + 32 + ni * 16 + l15, ks * 4 + l4);
        if (more) { STG(BT, colBase, 2, ktn, Bn); STG(BT, colBase, 3, ktn, Bn); }
        __builtin_amdgcn_s_setprio(1);
        #pragma unroll
        for (int mi = 0; mi < 4; ++mi)
            #pragma unroll
            for (int ni = 0; ni < 2; ++ni)
                #pragma unroll
                for (int ks = 0; ks < 2; ++ks)
                    acc[mi][2 + ni] = __builtin_amdgcn_mfma_f32_16x16x32_bf16(
                        fa[mi][ks], fb[1][ni][ks], acc[mi][2 + ni], 0, 0, 0);
        __builtin_amdgcn_s_setprio(0);
        if (more) { VMW4_; } else { VMW0_; }
        FENCE_; __builtin_amdgcn_s_barrier();
        __builtin_amdgcn_sched_barrier(0);

        // ---- C3: read fa1 (A1/A3 now visible), stage A0,A2(t+1), MFMA bottom-left ----
        #pragma unroll
        for (int mi = 0; mi < 4; ++mi)
            #pragma unroll
            for (int ks = 0; ks < 2; ++ks)
                fa[mi][ks] = RDF(Ab, wm * 128 + 64 + mi * 16 + l15, ks * 4 + l4);
        if (more) { STG(A, rowBase, 0, ktn, An); STG(A, rowBase, 2, ktn, An); }
        __builtin_amdgcn_s_setprio(1);
        #pragma unroll
        for (int mi = 0; mi < 4; ++mi)
            #pragma unroll
            for (int ni = 0; ni < 2; ++ni)
                #pragma unroll
                for (int ks = 0; ks < 2; ++ks)
                    acc[4 + mi][ni] = __builtin_amdgcn_mfma_f32_16x16x32_bf16(
                        fa[mi][ks], fb[0][ni][ks], acc[4 + mi][ni], 0, 0, 0);
        __builtin_amdgcn_s_setprio(0);

        // ---- C4: stage A1,A3(t+1), MFMA bottom-right; end sync ----
        if (more) { STG(A, rowBase, 1, ktn, An); STG(A, rowBase, 3, ktn, An); }
        __builtin_amdgcn_s_setprio(1);
        #pragma unroll
        for (int mi = 0; mi < 4; ++mi)
            #pragma unroll
            for (int ni = 0; ni < 2; ++ni)
                #pragma unroll
                for (int ks = 0; ks < 2; ++ks)
                    acc[4 + mi][2 + ni] = __builtin_amdgcn_mfma_f32_16x16x32_bf16(
                        fa[mi][ks], fb[1][ni][ks], acc[4 + mi][2 + ni], 0, 0, 0);
        __builtin_amdgcn_s_setprio(0);
        if (more) { VMW2_; }
        FENCE_; __builtin_amdgcn_s_barrier();
        __builtin_amdgcn_sched_barrier(0);

        cur ^= 1;
    }
    #undef RDF
    #undef STG

    // ---------------- epilogue ----------------
    const int row0 = rowBase + wm * 128;
    const int c0   = colBase + wn * 64;
    if (MODE == 0) {
        #pragma unroll
        for (int m = 0; m < 8; ++m) {
            int mr = (m >> 2) * 64 + (m & 3) * 16;
            #pragma unroll
            for (int n = 0; n < 4; ++n) {
                int nc = (n >> 1) * 32 + (n & 1) * 16;
                #pragma unroll
                for (int r = 0; r < 4; ++r) {
                    int row = row0 + mr + l4 * 4 + r;
                    int col = c0 + nc + l15;
                    Cf[(size_t)row * N + col] = acc[m][n][r];
                }
            }
        }
    } else {
        const int which = c0 >> 11;               // 0:q 1:k 2:v 3:gate
        const int h     = (c0 >> 7) & 15;
        const int d0    = c0 & 127;
        const int b     = row0 >> 12;
        const int bh    = b * NH_ + h;
        #pragma unroll
        for (int m = 0; m < 8; ++m) {
            int mr = (m >> 2) * 64 + (m & 3) * 16;
            int sr0 = (row0 & 4095) + mr + l4 * 4;
            #pragma unroll
            for (int n = 0; n < 4; ++n) {
                int nc = (n >> 1) * 32 + (n & 1) * 16;
                float x0 = acc[m][n][0], x1 = acc[m][n][1];
                float x2 = acc[m][n][2], x3 = acc[m][n][3];
                if (which == 3) {
                    int col_g = (c0 - 6144) + nc + l15;
                    ushort_t* gp = gateo + (size_t)(row0 + mr + l4 * 4) * H_ + col_g;
                    gp[0]       = f2bf(1.f / (1.f + __expf(-x0)));
                    gp[H_]      = f2bf(1.f / (1.f + __expf(-x1)));
                    gp[2 * H_]  = f2bf(1.f / (1.f + __expf(-x2)));
                    gp[3 * H_]  = f2bf(1.f / (1.f + __expf(-x3)));
                } else {
                    int d = d0 + nc + l15;
                    float s0 = x0 / (1.f + __expf(-x0));
                    float s1 = x1 / (1.f + __expf(-x1));
                    float s2 = x2 / (1.f + __expf(-x2));
                    float s3 = x3 / (1.f + __expf(-x3));
                    if (which == 0) {
                        ushort_t* qp = qo + ((size_t)bh * S_ + sr0) * HD_ + d;
                        qp[0]        = f2bf(s0);
                        qp[HD_]      = f2bf(s1);
                        qp[2 * HD_]  = f2bf(s2);
                        qp[3 * HD_]  = f2bf(s3);
                    } else if (which == 1) {
                        u16x4 pk = { f2bf(s0), f2bf(s1), f2bf(s2), f2bf(s3) };
                        ushort_t* kp = ko + ((size_t)bh * S_ + sr0) * HD_ + d;
                        kp[0] = pk[0]; kp[HD_] = pk[1]; kp[2 * HD_] = pk[2]; kp[3 * HD_] = pk[3];
                        *reinterpret_cast<u16x4*>(&kTo[((size_t)bh * HD_ + d) * S_ + sr0]) = pk;
                    } else {
                        float mk0 = mask[b * S_ + sr0],     mk1 = mask[b * S_ + sr0 + 1];
                        float mk2 = mask[b * S_ + sr0 + 2], mk3 = mask[b * S_ + sr0 + 3];
                        u16x4 pk = { f2bf(s0 * mk0), f2bf(s1 * mk1), f2bf(s2 * mk2), f2bf(s3 * mk3) };
                        *reinterpret_cast<u16x4*>(&vTo[((size_t)bh * HD_ + d) * S_ + sr0]) = pk;
                    }
                }
            }
        }
    }
}

// ---------------------------------------------------------------------------
// Per-chunk KV state contribution (MFMA, transposed output) — unchanged.
// ---------------------------------------------------------------------------
__global__ __launch_bounds__(256)
void kv_chunk_mfma(const ushort_t* __restrict__ kT, const ushort_t* __restrict__ vT,
                   const float* __restrict__ slope, ushort_t* __restrict__ kvT)
{
    const int c = blockIdx.x, bh = blockIdx.y;
    const float s = slope[bh & 15];
    const int tid = threadIdx.x, lane = tid & 63, w = tid >> 6;
    const int l15 = lane & 15, l4 = lane >> 4;
    __shared__ float dec[BLOCK_];
    __shared__ __align__(16) ushort_t VTl[128 * 64];
    __shared__ __align__(16) ushort_t KTl[128 * 64];
    dec[tid] = __expf(-s * (float)(BLOCK_ - 1 - tid));

    frag_cd acc[2][8];
    #pragma unroll
    for (int mf = 0; mf < 2; ++mf)
        #pragma unroll
        for (int df = 0; df < 8; ++df) acc[mf][df] = 0.f;

    for (int nt = 0; nt < 4; ++nt) {
        __syncthreads();
        #pragma unroll
        for (int i = 0; i < 4; ++i) {
            int u = tid + i * 256;
            int row = u >> 3, slot = u & 7;
            size_t gsrc = ((size_t)bh * HD_ + row) * S_ + c * BLOCK_ + nt * 64 + slot * 8;
            frag_ab v8 = *reinterpret_cast<const frag_ab*>(vT + gsrc);
            *reinterpret_cast<frag_ab*>((char*)VTl + row * 128 + ((slot * 16) ^ ((row & 7) << 4))) = v8;
            frag_ab k8 = *reinterpret_cast<const frag_ab*>(kT + gsrc);
            frag_ab kd;
            #pragma unroll
            for (int j = 0; j < 8; ++j)
                kd[j] = (short)f2bf(bf2f((ushort_t)k8[j]) * dec[nt * 64 + slot * 8 + j]);
            *reinterpret_cast<frag_ab*>((char*)KTl + row * 128 + ((slot * 16) ^ ((row & 7) << 4))) = kd;
        }
        __syncthreads();
        #pragma unroll
        for (int ks = 0; ks < 2; ++ks) {
            frag_ab a[2];
            #pragma unroll
            for (int mf = 0; mf < 2; ++mf)
                a[mf] = *reinterpret_cast<const frag_ab*>(
                    (char*)VTl + (w * 32 + mf * 16 + l15) * 128 + ((ks * 64 + l4 * 16) ^ ((l15 & 7) << 4)));
            #pragma unroll
            for (int df = 0; df < 8; ++df) {
                frag_ab bk = *reinterpret_cast<const frag_ab*>(
                    (char*)KTl + (df * 16 + l15) * 128 + ((ks * 64 + l4 * 16) ^ ((l15 & 7) << 4)));
                acc[0][df] = __builtin_amdgcn_mfma_f32_16x16x32_bf16(a[0], bk, acc[0][df], 0, 0, 0);
                acc[1][df] = __builtin_amdgcn_mfma_f32_16x16x32_bf16(a[1], bk, acc[1][df], 0, 0, 0);
            }
        }
    }
    ushort_t* out = kvT + ((size_t)bh * NC_ + c) * 16384;
    #pragma unroll
    for (int mf = 0; mf < 2; ++mf)
        #pragma unroll
        for (int df = 0; df < 8; ++df)
            #pragma unroll
            for (int r = 0; r < 4; ++r) {
                int e = w * 32 + mf * 16 + l4 * 4 + r;
                int d = df * 16 + l15;
                out[e * 128 + d] = f2bf(acc[mf][df][r]);
            }
}

// ---------------------------------------------------------------------------
// Prefix scan over chunks — unchanged.
// ---------------------------------------------------------------------------
__global__ __launch_bounds__(256)
void kv_scan_kernel(const float* __restrict__ slope, const ushort_t* __restrict__ kvT,
                    ushort_t* __restrict__ sT)
{
    const int es = blockIdx.x, bh = blockIdx.y;
    const float s = slope[bh & 15];
    const float bd = __expf(-s * (float)BLOCK_);
    const int tid = threadIdx.x;
    float st[16];
    #pragma unroll
    for (int i = 0; i < 16; ++i) st[i] = 0.f;
    for (int c = 0; c < NC_; ++c) {
        const ushort_t* p = kvT + ((size_t)bh * NC_ + c) * 16384;
        ushort_t* qp = sT + ((size_t)bh * NC_ + c) * 16384;
        #pragma unroll
        for (int i = 0; i < 16; ++i) {
            int lin = tid + i * 256;
            int off = (lin >> 5) * 128 + es * 32 + (lin & 31);
            float x = bf2f(p[off]);
            qp[off] = f2bf(st[i]);
            st[i] = bd * st[i] + x;
        }
    }
}

// ---------------------------------------------------------------------------
// MFMA attention per chunk — unchanged.
// ---------------------------------------------------------------------------
__global__ __launch_bounds__(512)
void attn_mfma(const ushort_t* __restrict__ q, const ushort_t* __restrict__ k,
               const ushort_t* __restrict__ vT, const ushort_t* __restrict__ sT,
               const float* __restrict__ slope, float* __restrict__ o)
{
    const int c = blockIdx.x, bh = blockIdx.y;
    const int h = bh & 15, b = bh >> 4;
    const float s = slope[h];
    const int tid = threadIdx.x, lane = tid & 63, w = tid >> 6;
    const int l15 = lane & 15, l4 = lane >> 4;

    __shared__ __align__(16) ushort_t SH[16384];
    __shared__ __align__(16) ushort_t P[8][2048];

    frag_ab aq[2][4];
    #pragma unroll
    for (int mf = 0; mf < 2; ++mf)
        #pragma unroll
        for (int ks = 0; ks < 4; ++ks) {
            int row = c * BLOCK_ + w * 32 + mf * 16 + l15;
            aq[mf][ks] = *reinterpret_cast<const frag_ab*>(
                q + ((size_t)bh * S_ + row) * HD_ + ks * 32 + l4 * 8);
        }

    frag_cd oa[2][8];
    #pragma unroll
    for (int mf = 0; mf < 2; ++mf)
        #pragma unroll
        for (int ef = 0; ef < 8; ++ef) oa[mf][ef] = 0.f;

    const int wrow = w * 32;
    for (int nt = 0; nt < 4; ++nt) {
        __syncthreads();
        #pragma unroll
        for (int i = 0; i < 2; ++i) {
            int u = tid + i * 512;
            int n = u >> 4, slot = u & 15;
            frag_ab k8 = *reinterpret_cast<const frag_ab*>(
                k + ((size_t)bh * S_ + c * BLOCK_ + nt * 64 + n) * HD_ + slot * 8);
            *reinterpret_cast<frag_ab*>((char*)SH + n * 256 + ((slot * 16) ^ ((n & 7) << 4))) = k8;
        }
        #pragma unroll
        for (int i = 0; i < 2; ++i) {
            int u = tid + i * 512;
            int e = u >> 3, slot = u & 7;
            frag_ab v8 = *reinterpret_cast<const frag_ab*>(
                vT + ((size_t)bh * HD_ + e) * S_ + c * BLOCK_ + nt * 64 + slot * 8);
            *reinterpret_cast<frag_ab*>((char*)SH + 16384 + e * 128 + ((slot * 16) ^ ((e & 7) << 4))) = v8;
        }
        __syncthreads();
        if (nt * 64 > wrow + 31) continue;

        frag_cd pacc[2][4];
        #pragma unroll
        for (int mf = 0; mf < 2; ++mf)
            #pragma unroll
            for (int nf = 0; nf < 4; ++nf) pacc[mf][nf] = 0.f;
        #pragma unroll
        for (int ks = 0; ks < 4; ++ks)
            #pragma unroll
            for (int nf = 0; nf < 4; ++nf) {
                frag_ab bk = *reinterpret_cast<const frag_ab*>(
                    (char*)SH + (nf * 16 + l15) * 256 + ((ks * 64 + l4 * 16) ^ ((l15 & 7) << 4)));
                pacc[0][nf] = __builtin_amdgcn_mfma_f32_16x16x32_bf16(aq[0][ks], bk, pacc[0][nf], 0, 0, 0);
                pacc[1][nf] = __builtin_amdgcn_mfma_f32_16x16x32_bf16(aq[1][ks], bk, pacc[1][nf], 0, 0, 0);
            }
        #pragma unroll
        for (int mf = 0; mf < 2; ++mf)
            #pragma unroll
            for (int nf = 0; nf < 4; ++nf)
                #pragma unroll
                for (int r = 0; r < 4; ++r) {
                    int m = mf * 16 + l4 * 4 + r;
                    int mrow = wrow + m;
                    int ncol = nt * 64 + nf * 16 + l15;
                    float pv = 0.f;
                    if (mrow >= ncol) pv = pacc[mf][nf][r] * __expf(s * (float)(ncol - mrow));
                    *reinterpret_cast<ushort_t*>(
                        (char*)&P[w][0] + m * 128 + (((nf * 16 + l15) * 2) ^ ((m & 7) << 4))) = f2bf(pv);
                }
        __builtin_amdgcn_sched_barrier(0);
        #pragma unroll
        for (int ks = 0; ks < 2; ++ks) {
            frag_ab ap[2];
            #pragma unroll
            for (int mf = 0; mf < 2; ++mf)
                ap[mf] = *reinterpret_cast<const frag_ab*>(
                    (char*)&P[w][0] + (mf * 16 + l15) * 128 + ((ks * 64 + l4 * 16) ^ ((l15 & 7) << 4)));
            #pragma unroll
            for (int ef = 0; ef < 8; ++ef) {
                frag_ab bv = *reinterpret_cast<const frag_ab*>(
                    (char*)SH + 16384 + (ef * 16 + l15) * 128 + ((ks * 64 + l4 * 16) ^ ((l15 & 7) << 4)));
                oa[0][ef] = __builtin_amdgcn_mfma_f32_16x16x32_bf16(ap[0], bv, oa[0][ef], 0, 0, 0);
                oa[1][ef] = __builtin_amdgcn_mfma_f32_16x16x32_bf16(ap[1], bv, oa[1][ef], 0, 0, 0);
            }
        }
    }

    __syncthreads();
    #pragma unroll
    for (int i = 0; i < 4; ++i) {
        int u = tid + i * 512;
        int e = u >> 4, slot = u & 15;
        frag_ab s8 = *reinterpret_cast<const frag_ab*>(
            sT + ((size_t)(bh * NC_ + c)) * 16384 + e * 128 + slot * 8);
        *reinterpret_cast<frag_ab*>((char*)SH + e * 256 + ((slot * 16) ^ ((e & 7) << 4))) = s8;
    }
    __syncthreads();
    #pragma unroll
    for (int mf = 0; mf < 2; ++mf) {
        float qd = __expf(-s * (float)(wrow + mf * 16 + l15 + 1));
        #pragma unroll
        for (int ks = 0; ks < 4; ++ks) {
            frag_ab v = aq[mf][ks];
            #pragma unroll
            for (int j = 0; j < 8; ++j)
                v[j] = (short)f2bf(bf2f((ushort_t)v[j]) * qd);
            aq[mf][ks] = v;
        }
    }
    #pragma unroll
    for (int ks = 0; ks < 4; ++ks)
        #pragma unroll
        for (int ef = 0; ef < 8; ++ef) {
            frag_ab bs = *reinterpret_cast<const frag_ab*>(
                (char*)SH + (ef * 16 + l15) * 256 + ((ks * 64 + l4 * 16) ^ ((l15 & 7) << 4)));
            oa[0][ef] = __builtin_amdgcn_mfma_f32_16x16x32_bf16(aq[0][ks], bs, oa[0][ef], 0, 0, 0);
            oa[1][ef] = __builtin_amdgcn_mfma_f32_16x16x32_bf16(aq[1][ks], bs, oa[1][ef], 0, 0, 0);
        }
    #pragma unroll
    for (int mf = 0; mf < 2; ++mf)
        #pragma unroll
        for (int ef = 0; ef < 8; ++ef)
            #pragma unroll
            for (int r = 0; r < 4; ++r) {
                int row = c * BLOCK_ + wrow + mf * 16 + l4 * 4 + r;
                int col = h * HD_ + ef * 16 + l15;
                o[((size_t)(b * S_ + row)) * H_ + col] = oa[mf][ef][r];
            }
}

// ---------------------------------------------------------------------------
// RMSNorm * norm_weight * gate — unchanged.
// ---------------------------------------------------------------------------
__global__ __launch_bounds__(256)
void norm_gate_kernel(const float* __restrict__ o, const ushort_t* __restrict__ gate,
                      const float* __restrict__ nw, ushort_t* __restrict__ on)
{
    const int row = blockIdx.x;
    const int tid = threadIdx.x;
    const float* orow = o + (size_t)row * H_;
    const ushort_t* grow = gate + (size_t)row * H_;
    ushort_t* onrow = on + (size_t)row * H_;
    float vals[8];
    float ss = 0.f;
    #pragma unroll
    for (int i = 0; i < 8; ++i) {
        vals[i] = orow[tid + i * 256];
        ss += vals[i] * vals[i];
    }
    __shared__ float red[256];
    red[tid] = ss;
    __syncthreads();
    #pragma unroll
    for (int st = 128; st > 0; st >>= 1) {
        if (tid < st) red[tid] += red[tid + st];
        __syncthreads();
    }
    float scale = rsqrtf(red[0] * (1.f / (float)H_) + EPS_);
    #pragma unroll
    for (int i = 0; i < 8; ++i) {
        int cidx = tid + i * 256;
        onrow[cidx] = f2bf(vals[i] * scale * nw[cidx] * bf2f(grow[cidx]));
    }
}

// ---------------------------------------------------------------------------
extern "C" void kernel_launch(void* const* d_in, const int* in_sizes, int n_in,
                              void* d_out, int out_size, void* d_ws, size_t ws_size,
                              hipStream_t stream)
{
    const float* hidden = (const float*)d_in[0];
    const float* mask   = (const float*)d_in[1];
    const float* slope  = (const float*)d_in[2];
    const float* w_qkv  = (const float*)d_in[3];
    const float* w_gate = (const float*)d_in[4];
    const float* w_out  = (const float*)d_in[5];
    const float* nw     = (const float*)d_in[6];

    const size_t MH = (size_t)M_ * H_;                 // 16,777,216 elements
    ushort_t* hid_bf  = (ushort_t*)d_ws;
    ushort_t* on_ws   = hid_bf;
    // r1: wqkvT (6144x2048) + wgateT (2048x2048) contiguous = BT[8192][2048]
    ushort_t* wqkvT   = hid_bf + MH;
    ushort_t* wgateT  = wqkvT + (size_t)6144 * 2048;
    ushort_t* kvT_ws  = wqkvT;
    ushort_t* sT_ws   = wqkvT + MH / 2;
    ushort_t* woutT   = wqkvT;
    ushort_t* q_ws    = hid_bf + 2 * MH;
    ushort_t* k_ws    = q_ws + MH;
    ushort_t* vT_ws   = k_ws + MH;
    ushort_t* gate_ws = vT_ws + MH;
    ushort_t* kT_ws   = (ushort_t*)d_out;
    float*    o_f32   = (float*)d_out;

    dim3 blk(256);
    cast_bf16_kernel<<<(MH / 4) / 256, blk, 0, stream>>>(hidden, hid_bf);
    transpose_cast_kernel<<<dim3(6144 / 32, 2048 / 32), blk, 0, stream>>>(w_qkv, wqkvT, 2048, 6144);
    transpose_cast_kernel<<<dim3(2048 / 32, 2048 / 32), blk, 0, stream>>>(w_gate, wgateT, 2048, 2048);
    // 1+2. combined qkv+gate GEMM (N=8192), 256^2 pipelined
    gemm256<2><<<dim3((M_ / 256) * (8192 / 256)), dim3(512), 0, stream>>>(
        hid_bf, wqkvT, M_, 8192, 2048,
        nullptr, q_ws, k_ws, kT_ws, vT_ws, gate_ws, mask);
    // 3. per-chunk KV^T contributions
    kv_chunk_mfma<<<dim3(NC_, B_ * NH_), blk, 0, stream>>>(kT_ws, vT_ws, slope, kvT_ws);
    // 4. prefix scan -> S^T per chunk
    kv_scan_kernel<<<dim3(4, B_ * NH_), blk, 0, stream>>>(slope, kvT_ws, sT_ws);
    // 5. attention -> o f32 into d_out
    attn_mfma<<<dim3(NC_, B_ * NH_), dim3(512), 0, stream>>>(
        q_ws, k_ws, vT_ws, sT_ws, slope, o_f32);
    // prep final weight (kvT dead; sT untouched)
    transpose_cast_kernel<<<dim3(2048 / 32, 2048 / 32), blk, 0, stream>>>(w_out, woutT, 2048, 2048);
    // 6. RMSNorm * nw * gate -> bf16 o_n
    norm_gate_kernel<<<M_, blk, 0, stream>>>(o_f32, gate_ws, nw, on_ws);
    // 7. out = o_n @ w_out (256^2 pipelined, f32 C)
    gemm256<0><<<dim3((M_ / 256) * (2048 / 256)), dim3(512), 0, stream>>>(
        on_ws, woutT, M_, 2048, 2048,
        (float*)d_out, nullptr, nullptr, nullptr, nullptr, nullptr, nullptr);
}